// Round 1
// baseline (784.432 us; speedup 1.0000x reference)
//
#include <hip/hip_runtime.h>
#include <hip/hip_bf16.h>
#include <cstdint>
#include <cstddef>

// Problem constants (fixed by reference)
#define B_    2
#define S_    1024
#define HID_  4096
#define NH_   32
#define NKV_  8
#define HD_   128
#define G_    4
#define PAST_ 1024
#define L_    2048
#define NQKV_ 6144   // NH*HD + 2*NKV*HD

typedef __bf16 bf16_t;
typedef bf16_t bf16x8 __attribute__((ext_vector_type(8)));
typedef float  f32x4  __attribute__((ext_vector_type(4)));

__device__ __forceinline__ void gload_lds16(const bf16_t* g, bf16_t* l) {
  __builtin_amdgcn_global_load_lds(
      (const __attribute__((address_space(1))) void*)g,
      (__attribute__((address_space(3))) void*)l, 16, 0, 0);
}

// ---------------------------------------------------------------------------
// fp32 -> bf16 elementwise convert (8 elems/thread)
// ---------------------------------------------------------------------------
__global__ __launch_bounds__(256) void cvt_bf16x8(const float* __restrict__ src,
                                                  bf16_t* __restrict__ dst) {
  size_t i = ((size_t)blockIdx.x * 256 + threadIdx.x) * 8;
  f32x4 a = *(const f32x4*)(src + i);
  f32x4 b = *(const f32x4*)(src + i + 4);
  bf16x8 o;
#pragma unroll
  for (int j = 0; j < 4; ++j) o[j] = (bf16_t)a[j];
#pragma unroll
  for (int j = 0; j < 4; ++j) o[4 + j] = (bf16_t)b[j];
  *(bf16x8*)(dst + i) = o;
}

// ---------------------------------------------------------------------------
// fp32 [R][C] -> bf16 [C][R] tiled transpose-convert
// ---------------------------------------------------------------------------
__global__ __launch_bounds__(256) void transpose_cvt(const float* __restrict__ src,
                                                     bf16_t* __restrict__ dst,
                                                     int R, int C) {
  __shared__ float T[64][65];
  const int tid = threadIdx.x;
  const int c0 = blockIdx.x * 64;
  const int r0 = blockIdx.y * 64;
#pragma unroll
  for (int i = 0; i < 16; ++i) {
    int idx = i * 256 + tid;
    int lr = idx >> 6, lc = idx & 63;
    T[lr][lc] = src[(size_t)(r0 + lr) * C + c0 + lc];
  }
  __syncthreads();
#pragma unroll
  for (int i = 0; i < 16; ++i) {
    int idx = i * 256 + tid;
    int lr = idx >> 6, lc = idx & 63;
    dst[(size_t)(c0 + lr) * R + r0 + lc] = (bf16_t)T[lc][lr];
  }
}

// ---------------------------------------------------------------------------
// bf16 GEMM, m97 structure: C[M][N] = A[M][K] * Bt[N][K]^T
// 128x128 tile, BK=32, 4 waves (2x2), 4x4 16x16x32 frags per wave
// ---------------------------------------------------------------------------
template <bool OUT_BF16>
__global__ __launch_bounds__(256) void gemm_bt(const bf16_t* __restrict__ A,
                                               const bf16_t* __restrict__ Bt,
                                               void* __restrict__ C, int N, int K) {
  __shared__ bf16_t As[128 * 32];
  __shared__ bf16_t Bs[128 * 32];
  const int tid = threadIdx.x;
  const int lane = tid & 63;
  const int w = tid >> 6;
  const int wm = w >> 1, wn = w & 1;
  const int m0 = blockIdx.y * 128;
  const int n0 = blockIdx.x * 128;
  const int g = lane >> 4;
  const int r16 = lane & 15;

  f32x4 acc[4][4] = {};

  for (int kt = 0; kt < K; kt += 32) {
    __syncthreads();
#pragma unroll
    for (int j = 0; j < 2; ++j) {
      int cbase = (w * 2 + j) * 64;
      int chunk = cbase + lane;
      gload_lds16(A + (size_t)(m0 + (chunk >> 2)) * K + kt + (chunk & 3) * 8,
                  As + cbase * 8);
      gload_lds16(Bt + (size_t)(n0 + (chunk >> 2)) * K + kt + (chunk & 3) * 8,
                  Bs + cbase * 8);
    }
    __syncthreads();
    bf16x8 af[4], bf[4];
#pragma unroll
    for (int i = 0; i < 4; ++i)
      af[i] = *(const bf16x8*)&As[(wm * 64 + i * 16 + r16) * 32 + g * 8];
#pragma unroll
    for (int i = 0; i < 4; ++i)
      bf[i] = *(const bf16x8*)&Bs[(wn * 64 + i * 16 + r16) * 32 + g * 8];
#pragma unroll
    for (int i = 0; i < 4; ++i)
#pragma unroll
      for (int j2 = 0; j2 < 4; ++j2)
        acc[i][j2] = __builtin_amdgcn_mfma_f32_16x16x32_bf16(af[i], bf[j2],
                                                             acc[i][j2], 0, 0, 0);
  }

#pragma unroll
  for (int i = 0; i < 4; ++i)
#pragma unroll
    for (int j2 = 0; j2 < 4; ++j2)
#pragma unroll
      for (int r = 0; r < 4; ++r) {
        int row = m0 + wm * 64 + i * 16 + g * 4 + r;
        int col = n0 + wn * 64 + j2 * 16 + r16;
        if (OUT_BF16)
          ((bf16_t*)C)[(size_t)row * N + col] = (bf16_t)acc[i][j2][r];
        else
          ((float*)C)[(size_t)row * N + col] = acc[i][j2][r];
      }
}

// ---------------------------------------------------------------------------
// RoPE on q,k from QKV buffer; scatter into Qb[B,NH,S,HD], Kb[B,NKV,L,HD] (new part)
// grid (tokens, 40 heads), block 128
// ---------------------------------------------------------------------------
__global__ __launch_bounds__(128) void rope_pack(const bf16_t* __restrict__ QKV,
                                                 const float* __restrict__ rope,
                                                 bf16_t* __restrict__ Qb,
                                                 bf16_t* __restrict__ Kb) {
  const int tok = blockIdx.x;
  const int head = blockIdx.y;
  const int d = threadIdx.x;
  const int b = tok >> 10, s = tok & 1023;
  const int pos = PAST_ + s;
  const int off = head < NH_ ? head * HD_ : HID_ + (head - NH_) * HD_;
  const bf16_t* row = QKV + (size_t)tok * NQKV_;
  float x = (float)row[off + d];
  int dp = d < 64 ? d + 64 : d - 64;
  float xp = (float)row[off + dp];
  float c = rope[(size_t)(pos * 2) * HD_ + d];
  float sn = rope[(size_t)(pos * 2 + 1) * HD_ + d];
  float out = d < 64 ? x * c - xp * sn : x * c + xp * sn;
  if (head < NH_)
    Qb[((size_t)(b * NH_ + head) * S_ + s) * HD_ + d] = (bf16_t)out;
  else
    Kb[((size_t)(b * NKV_ + (head - NH_)) * L_ + PAST_ + s) * HD_ + d] = (bf16_t)out;
}

// ---------------------------------------------------------------------------
// Past KV: gather kv_cache[kv_lut] for l<PAST -> Kb direct, Vt transposed
// grid B*NKV*(PAST/64) = 256, block 256
// ---------------------------------------------------------------------------
__global__ __launch_bounds__(256) void past_kv(const float* __restrict__ cache,
                                               const int* __restrict__ kv_lut,
                                               bf16_t* __restrict__ Kb,
                                               bf16_t* __restrict__ Vt) {
  __shared__ bf16_t Vs[128][72];
  const int tid = threadIdx.x;
  const int lt = blockIdx.x & 15;
  const int h = (blockIdx.x >> 4) & 7;
  const int b = blockIdx.x >> 7;
  const int l0 = lt * 64;
#pragma unroll
  for (int i = 0; i < 32; ++i) {
    int idx = i * 256 + tid;
    int l = idx >> 7, d = idx & 127;
    int slot = kv_lut[b * L_ + l0 + l];
    float kv = cache[((size_t)slot * 2 * NKV_ + h) * HD_ + d];
    float vv = cache[(((size_t)slot * 2 + 1) * NKV_ + h) * HD_ + d];
    Kb[((size_t)(b * NKV_ + h) * L_ + l0 + l) * HD_ + d] = (bf16_t)kv;
    Vs[d][l] = (bf16_t)vv;
  }
  __syncthreads();
#pragma unroll
  for (int i = 0; i < 32; ++i) {
    int idx = i * 256 + tid;
    int d = idx >> 6, l = idx & 63;
    Vt[((size_t)(b * NKV_ + h) * HD_ + d) * L_ + l0 + l] = Vs[d][l];
  }
}

// ---------------------------------------------------------------------------
// New-token V: QKV v-part -> Vt transposed (l = PAST+s)
// grid B*NKV*(S/64) = 256, block 256
// ---------------------------------------------------------------------------
__global__ __launch_bounds__(256) void v_pack(const bf16_t* __restrict__ QKV,
                                              bf16_t* __restrict__ Vt) {
  __shared__ bf16_t Vs[128][72];
  const int tid = threadIdx.x;
  const int st = blockIdx.x & 15;
  const int h = (blockIdx.x >> 4) & 7;
  const int b = blockIdx.x >> 7;
  const int s0 = st * 64;
#pragma unroll
  for (int i = 0; i < 32; ++i) {
    int idx = i * 256 + tid;
    int sl = idx >> 7, d = idx & 127;
    Vs[d][sl] = QKV[(size_t)(b * S_ + s0 + sl) * NQKV_ + HID_ + NKV_ * HD_ + h * HD_ + d];
  }
  __syncthreads();
#pragma unroll
  for (int i = 0; i < 32; ++i) {
    int idx = i * 256 + tid;
    int d = idx >> 6, l = idx & 63;
    Vt[((size_t)(b * NKV_ + h) * HD_ + d) * L_ + PAST_ + s0 + l] = Vs[d][l];
  }
}

// ---------------------------------------------------------------------------
// Flash attention: grid B*NH*(S/64)=1024 blocks, 4 waves, 16 q-rows/wave
// ---------------------------------------------------------------------------
__global__ __launch_bounds__(256) void attn(const bf16_t* __restrict__ Qb,
                                            const bf16_t* __restrict__ Kb,
                                            const bf16_t* __restrict__ Vt,
                                            bf16_t* __restrict__ Ctx) {
  __shared__ bf16_t P_lds[4][16][72];
  const int tid = threadIdx.x;
  const int lane = tid & 63;
  const int w = tid >> 6;
  const int g = lane >> 4;
  const int r16 = lane & 15;

  const int qt = blockIdx.x & 15;
  const int h = (blockIdx.x >> 4) & 31;
  const int b = blockIdx.x >> 9;
  const int kh = h >> 2;  // GQA group

  const int s0w = qt * 64 + w * 16;

  const bf16_t* qp = Qb + ((size_t)(b * NH_ + h) * S_ + s0w + r16) * HD_ + g * 8;
  bf16x8 qf[4];
#pragma unroll
  for (int ks = 0; ks < 4; ++ks) qf[ks] = *(const bf16x8*)(qp + ks * 32);

  const bf16_t* kbase = Kb + (size_t)(b * NKV_ + kh) * L_ * HD_;
  const bf16_t* vbase = Vt + (size_t)(b * NKV_ + kh) * HD_ * L_;

  float m_r[4], s_r[4];
  f32x4 acc_o[8] = {};
#pragma unroll
  for (int r = 0; r < 4; ++r) { m_r[r] = -1e30f; s_r[r] = 0.f; }

  const float scale = 0.08838834764831845f;  // 1/sqrt(HD)
  const int qpos_base = PAST_ + s0w;
  const int ntiles = (qpos_base + 15) / 64 + 1;

  for (int t = 0; t < ntiles; ++t) {
    const int lt = t * 64;
    const bool need_mask = (lt + 63) > qpos_base;

    f32x4 sc[4] = {};
#pragma unroll
    for (int nt = 0; nt < 4; ++nt) {
      const bf16_t* kp = kbase + (size_t)(lt + nt * 16 + r16) * HD_ + g * 8;
#pragma unroll
      for (int ks = 0; ks < 4; ++ks) {
        bf16x8 kf = *(const bf16x8*)(kp + ks * 32);
        sc[nt] = __builtin_amdgcn_mfma_f32_16x16x32_bf16(qf[ks], kf, sc[nt], 0, 0, 0);
      }
    }

    float sv[4][4];
    float rowmax[4] = {-1e30f, -1e30f, -1e30f, -1e30f};
#pragma unroll
    for (int nt = 0; nt < 4; ++nt)
#pragma unroll
      for (int r = 0; r < 4; ++r) {
        float v = sc[nt][r] * scale;
        if (need_mask) {
          int lg = lt + nt * 16 + r16;
          int qpos = qpos_base + g * 4 + r;
          if (lg > qpos) v = -1e30f;
        }
        sv[nt][r] = v;
        rowmax[r] = fmaxf(rowmax[r], v);
      }
#pragma unroll
    for (int r = 0; r < 4; ++r) {
      rowmax[r] = fmaxf(rowmax[r], __shfl_xor(rowmax[r], 1, 64));
      rowmax[r] = fmaxf(rowmax[r], __shfl_xor(rowmax[r], 2, 64));
      rowmax[r] = fmaxf(rowmax[r], __shfl_xor(rowmax[r], 4, 64));
      rowmax[r] = fmaxf(rowmax[r], __shfl_xor(rowmax[r], 8, 64));
    }
    float alpha[4], psum[4];
#pragma unroll
    for (int r = 0; r < 4; ++r) {
      float newm = fmaxf(m_r[r], rowmax[r]);
      alpha[r] = __expf(m_r[r] - newm);
      m_r[r] = newm;
      psum[r] = 0.f;
    }
    float pv_[4][4];
#pragma unroll
    for (int nt = 0; nt < 4; ++nt)
#pragma unroll
      for (int r = 0; r < 4; ++r) {
        float p = __expf(sv[nt][r] - m_r[r]);
        pv_[nt][r] = p;
        psum[r] += p;
      }
#pragma unroll
    for (int r = 0; r < 4; ++r) {
      psum[r] += __shfl_xor(psum[r], 1, 64);
      psum[r] += __shfl_xor(psum[r], 2, 64);
      psum[r] += __shfl_xor(psum[r], 4, 64);
      psum[r] += __shfl_xor(psum[r], 8, 64);
      s_r[r] = s_r[r] * alpha[r] + psum[r];
    }
#pragma unroll
    for (int d8 = 0; d8 < 8; ++d8)
#pragma unroll
      for (int r = 0; r < 4; ++r) acc_o[d8][r] *= alpha[r];

    // P (C/D layout) -> LDS, re-read as A-fragments
#pragma unroll
    for (int nt = 0; nt < 4; ++nt)
#pragma unroll
      for (int r = 0; r < 4; ++r)
        P_lds[w][g * 4 + r][nt * 16 + r16] = (bf16_t)pv_[nt][r];

#pragma unroll
    for (int ks2 = 0; ks2 < 2; ++ks2) {
      bf16x8 pa = *(const bf16x8*)&P_lds[w][r16][ks2 * 32 + g * 8];
#pragma unroll
      for (int d8 = 0; d8 < 8; ++d8) {
        bf16x8 vf = *(const bf16x8*)(vbase + (size_t)(d8 * 16 + r16) * L_ +
                                     lt + ks2 * 32 + g * 8);
        acc_o[d8] = __builtin_amdgcn_mfma_f32_16x16x32_bf16(pa, vf, acc_o[d8], 0, 0, 0);
      }
    }
  }

#pragma unroll
  for (int r = 0; r < 4; ++r) s_r[r] = 1.f / s_r[r];
#pragma unroll
  for (int d8 = 0; d8 < 8; ++d8)
#pragma unroll
    for (int r = 0; r < 4; ++r) {
      int tok = b * S_ + s0w + g * 4 + r;
      int col = h * HD_ + d8 * 16 + r16;
      Ctx[(size_t)tok * HID_ + col] = (bf16_t)(acc_o[d8][r] * s_r[r]);
    }
}

// ---------------------------------------------------------------------------
extern "C" void kernel_launch(void* const* d_in, const int* in_sizes, int n_in,
                              void* d_out, int out_size, void* d_ws, size_t ws_size,
                              hipStream_t stream) {
  const float* hidden = (const float*)d_in[0];
  const float* kv_cache = (const float*)d_in[1];
  const float* rope = (const float*)d_in[2];
  const float* Wq = (const float*)d_in[3];
  const float* Wk = (const float*)d_in[4];
  const float* Wv = (const float*)d_in[5];
  const float* Wo = (const float*)d_in[6];
  const int* kv_lut = (const int*)d_in[9];
  float* out = (float*)d_out;

  // workspace layout (bf16 elements)
  bf16_t* Xb = (bf16_t*)d_ws;                      //  2048*4096
  bf16_t* Wcat = Xb + (size_t)2048 * 4096;         //  6144*4096 (B^T: [n][k])
  bf16_t* Wot = Wcat + (size_t)6144 * 4096;        //  4096*4096
  bf16_t* QKVb = Wot + (size_t)4096 * 4096;        //  2048*6144
  bf16_t* Qb = QKVb + (size_t)2048 * 6144;         //  B*NH*S*HD
  bf16_t* Kb = Qb + (size_t)B_ * NH_ * S_ * HD_;   //  B*NKV*L*HD
  bf16_t* Vt = Kb + (size_t)B_ * NKV_ * L_ * HD_;  //  B*NKV*HD*L
  bf16_t* Ctx = Xb;                                //  reuse (Xb dead after GEMM1)

  // 1. converts / transposes
  cvt_bf16x8<<<4096, 256, 0, stream>>>(hidden, Xb);
  transpose_cvt<<<dim3(64, 64), 256, 0, stream>>>(Wq, Wcat, 4096, 4096);
  transpose_cvt<<<dim3(16, 64), 256, 0, stream>>>(Wk, Wcat + (size_t)4096 * 4096, 4096, 1024);
  transpose_cvt<<<dim3(16, 64), 256, 0, stream>>>(Wv, Wcat + (size_t)5120 * 4096, 4096, 1024);
  transpose_cvt<<<dim3(64, 64), 256, 0, stream>>>(Wo, Wot, 4096, 4096);

  // 2. QKV projection
  gemm_bt<true><<<dim3(48, 16), 256, 0, stream>>>(Xb, Wcat, QKVb, NQKV_, HID_);

  // 3. RoPE + KV pack
  rope_pack<<<dim3(2048, 40), 128, 0, stream>>>(QKVb, rope, Qb, Kb);
  past_kv<<<256, 256, 0, stream>>>(kv_cache, kv_lut, Kb, Vt);
  v_pack<<<256, 256, 0, stream>>>(QKVb, Vt);

  // 4. attention
  attn<<<1024, 256, 0, stream>>>(Qb, Kb, Vt, Ctx);

  // 5. output projection -> fp32 d_out
  gemm_bt<false><<<dim3(32, 16), 256, 0, stream>>>(Ctx, Wot, out, HID_, HID_);
}

// Round 2
// 677.508 us; speedup vs baseline: 1.1578x; 1.1578x over previous
//
#include <hip/hip_runtime.h>
#include <hip/hip_bf16.h>
#include <cstdint>
#include <cstddef>

// Problem constants (fixed by reference)
#define B_    2
#define S_    1024
#define HID_  4096
#define NH_   32
#define NKV_  8
#define HD_   128
#define G_    4
#define PAST_ 1024
#define L_    2048
#define NQKV_ 6144   // NH*HD + 2*NKV*HD

typedef __bf16 bf16_t;
typedef bf16_t bf16x4 __attribute__((ext_vector_type(4)));
typedef bf16_t bf16x8 __attribute__((ext_vector_type(8)));
typedef float  f32x4  __attribute__((ext_vector_type(4)));

__device__ __forceinline__ void gload_lds16(const bf16_t* g, bf16_t* l) {
  __builtin_amdgcn_global_load_lds(
      (const __attribute__((address_space(1))) void*)g,
      (__attribute__((address_space(3))) void*)l, 16, 0, 0);
}

// ---------------------------------------------------------------------------
// fp32 -> bf16 elementwise convert (8 elems/thread)
// ---------------------------------------------------------------------------
__global__ __launch_bounds__(256) void cvt_bf16x8(const float* __restrict__ src,
                                                  bf16_t* __restrict__ dst) {
  size_t i = ((size_t)blockIdx.x * 256 + threadIdx.x) * 8;
  f32x4 a = *(const f32x4*)(src + i);
  f32x4 b = *(const f32x4*)(src + i + 4);
  bf16x8 o;
#pragma unroll
  for (int j = 0; j < 4; ++j) o[j] = (bf16_t)a[j];
#pragma unroll
  for (int j = 0; j < 4; ++j) o[4 + j] = (bf16_t)b[j];
  *(bf16x8*)(dst + i) = o;
}

// ---------------------------------------------------------------------------
// fp32 [R][C] -> bf16 [C][R] tiled transpose-convert
// ---------------------------------------------------------------------------
__global__ __launch_bounds__(256) void transpose_cvt(const float* __restrict__ src,
                                                     bf16_t* __restrict__ dst,
                                                     int R, int C) {
  __shared__ float T[64][65];
  const int tid = threadIdx.x;
  const int c0 = blockIdx.x * 64;
  const int r0 = blockIdx.y * 64;
#pragma unroll
  for (int i = 0; i < 16; ++i) {
    int idx = i * 256 + tid;
    int lr = idx >> 6, lc = idx & 63;
    T[lr][lc] = src[(size_t)(r0 + lr) * C + c0 + lc];
  }
  __syncthreads();
#pragma unroll
  for (int i = 0; i < 16; ++i) {
    int idx = i * 256 + tid;
    int lr = idx >> 6, lc = idx & 63;
    dst[(size_t)(c0 + lr) * R + r0 + lc] = (bf16_t)T[lc][lr];
  }
}

// ---------------------------------------------------------------------------
// bf16 GEMM, m97 structure: C[M][N] = A[M][K] * Bt[N][K]^T
// 128x128 tile, BK=32, 4 waves (2x2), 4x4 16x16x32 frags per wave
// ---------------------------------------------------------------------------
template <bool OUT_BF16>
__global__ __launch_bounds__(256) void gemm_bt(const bf16_t* __restrict__ A,
                                               const bf16_t* __restrict__ Bt,
                                               void* __restrict__ C, int N, int K) {
  __shared__ bf16_t As[128 * 32];
  __shared__ bf16_t Bs[128 * 32];
  const int tid = threadIdx.x;
  const int lane = tid & 63;
  const int w = tid >> 6;
  const int wm = w >> 1, wn = w & 1;
  const int m0 = blockIdx.y * 128;
  const int n0 = blockIdx.x * 128;
  const int g = lane >> 4;
  const int r16 = lane & 15;

  f32x4 acc[4][4] = {};

  for (int kt = 0; kt < K; kt += 32) {
    __syncthreads();
#pragma unroll
    for (int j = 0; j < 2; ++j) {
      int cbase = (w * 2 + j) * 64;
      int chunk = cbase + lane;
      gload_lds16(A + (size_t)(m0 + (chunk >> 2)) * K + kt + (chunk & 3) * 8,
                  As + cbase * 8);
      gload_lds16(Bt + (size_t)(n0 + (chunk >> 2)) * K + kt + (chunk & 3) * 8,
                  Bs + cbase * 8);
    }
    __syncthreads();
    bf16x8 af[4], bf[4];
#pragma unroll
    for (int i = 0; i < 4; ++i)
      af[i] = *(const bf16x8*)&As[(wm * 64 + i * 16 + r16) * 32 + g * 8];
#pragma unroll
    for (int i = 0; i < 4; ++i)
      bf[i] = *(const bf16x8*)&Bs[(wn * 64 + i * 16 + r16) * 32 + g * 8];
#pragma unroll
    for (int i = 0; i < 4; ++i)
#pragma unroll
      for (int j2 = 0; j2 < 4; ++j2)
        acc[i][j2] = __builtin_amdgcn_mfma_f32_16x16x32_bf16(af[i], bf[j2],
                                                             acc[i][j2], 0, 0, 0);
  }

#pragma unroll
  for (int i = 0; i < 4; ++i)
#pragma unroll
    for (int j2 = 0; j2 < 4; ++j2)
#pragma unroll
      for (int r = 0; r < 4; ++r) {
        int row = m0 + wm * 64 + i * 16 + g * 4 + r;
        int col = n0 + wn * 64 + j2 * 16 + r16;
        if (OUT_BF16)
          ((bf16_t*)C)[(size_t)row * N + col] = (bf16_t)acc[i][j2][r];
        else
          ((float*)C)[(size_t)row * N + col] = acc[i][j2][r];
      }
}

// ---------------------------------------------------------------------------
// RoPE on q,k from QKV buffer; scatter into Qb[B,NH,S,HD], Kb[B,NKV,L,HD] (new part)
// grid (tokens, 20), block 256 (2 heads per block)
// ---------------------------------------------------------------------------
__global__ __launch_bounds__(256) void rope_pack(const bf16_t* __restrict__ QKV,
                                                 const float* __restrict__ rope,
                                                 bf16_t* __restrict__ Qb,
                                                 bf16_t* __restrict__ Kb) {
  const int tok = blockIdx.x;
  const int head = blockIdx.y * 2 + (threadIdx.x >> 7);
  const int d = threadIdx.x & 127;
  const int b = tok >> 10, s = tok & 1023;
  const int pos = PAST_ + s;
  const int off = head < NH_ ? head * HD_ : HID_ + (head - NH_) * HD_;
  const bf16_t* row = QKV + (size_t)tok * NQKV_;
  float x = (float)row[off + d];
  int dp = d < 64 ? d + 64 : d - 64;
  float xp = (float)row[off + dp];
  float c = rope[(size_t)(pos * 2) * HD_ + d];
  float sn = rope[(size_t)(pos * 2 + 1) * HD_ + d];
  float out = d < 64 ? x * c - xp * sn : x * c + xp * sn;
  if (head < NH_)
    Qb[((size_t)(b * NH_ + head) * S_ + s) * HD_ + d] = (bf16_t)out;
  else
    Kb[((size_t)(b * NKV_ + (head - NH_)) * L_ + PAST_ + s) * HD_ + d] = (bf16_t)out;
}

// ---------------------------------------------------------------------------
// Past KV: gather kv_cache[kv_lut] for l<PAST -> Kb direct, Vt transposed
// grid B*NKV*(PAST/64) = 256, block 256
// ---------------------------------------------------------------------------
__global__ __launch_bounds__(256) void past_kv(const float* __restrict__ cache,
                                               const int* __restrict__ kv_lut,
                                               bf16_t* __restrict__ Kb,
                                               bf16_t* __restrict__ Vt) {
  __shared__ bf16_t Vs[128][72];
  const int tid = threadIdx.x;
  const int lt = blockIdx.x & 15;
  const int h = (blockIdx.x >> 4) & 7;
  const int b = blockIdx.x >> 7;
  const int l0 = lt * 64;
#pragma unroll
  for (int i = 0; i < 32; ++i) {
    int idx = i * 256 + tid;
    int l = idx >> 7, d = idx & 127;
    int slot = kv_lut[b * L_ + l0 + l];
    float kv = cache[((size_t)slot * 2 * NKV_ + h) * HD_ + d];
    float vv = cache[(((size_t)slot * 2 + 1) * NKV_ + h) * HD_ + d];
    Kb[((size_t)(b * NKV_ + h) * L_ + l0 + l) * HD_ + d] = (bf16_t)kv;
    Vs[d][l] = (bf16_t)vv;
  }
  __syncthreads();
#pragma unroll
  for (int i = 0; i < 32; ++i) {
    int idx = i * 256 + tid;
    int d = idx >> 6, l = idx & 63;
    Vt[((size_t)(b * NKV_ + h) * HD_ + d) * L_ + l0 + l] = Vs[d][l];
  }
}

// ---------------------------------------------------------------------------
// New-token V: QKV v-part -> Vt transposed (l = PAST+s)
// grid B*NKV*(S/64) = 256, block 256
// ---------------------------------------------------------------------------
__global__ __launch_bounds__(256) void v_pack(const bf16_t* __restrict__ QKV,
                                              bf16_t* __restrict__ Vt) {
  __shared__ bf16_t Vs[128][72];
  const int tid = threadIdx.x;
  const int st = blockIdx.x & 15;
  const int h = (blockIdx.x >> 4) & 7;
  const int b = blockIdx.x >> 7;
  const int s0 = st * 64;
#pragma unroll
  for (int i = 0; i < 32; ++i) {
    int idx = i * 256 + tid;
    int sl = idx >> 7, d = idx & 127;
    Vs[d][sl] = QKV[(size_t)(b * S_ + s0 + sl) * NQKV_ + HID_ + NKV_ * HD_ + h * HD_ + d];
  }
  __syncthreads();
#pragma unroll
  for (int i = 0; i < 32; ++i) {
    int idx = i * 256 + tid;
    int d = idx >> 6, l = idx & 63;
    Vt[((size_t)(b * NKV_ + h) * HD_ + d) * L_ + PAST_ + s0 + l] = Vs[d][l];
  }
}

// ---------------------------------------------------------------------------
// Flash attention, swapped-QK^T + defer-max + balanced q-tile pairing.
// grid 512 blocks = (qh,p)x(b,kh); 8 waves/block; wave = 16 q-rows.
//   id = (qh*8 + p)*16 + b*8 + kh  ->  id%8 == kh pins K/V to one XCD's L2.
//   waves 0-3 -> q-tile p, waves 4-7 -> q-tile 15-p: every block = 196 wave-tiles.
// Swapped QK^T: sc = mfma(K,Q) so each lane owns P[l-chunk][q=lane&15];
//   softmax reduce = 15 in-lane ops + 2 shuffles (vs 32 shuffles before).
// ---------------------------------------------------------------------------
__global__ __launch_bounds__(512) void attn(const bf16_t* __restrict__ Qb,
                                            const bf16_t* __restrict__ Kb,
                                            const bf16_t* __restrict__ Vt,
                                            bf16_t* __restrict__ Ctx) {
  __shared__ bf16_t P_lds[8][16][72];
  const int tid = threadIdx.x;
  const int lane = tid & 63;
  const int w = tid >> 6;
  const int g = lane >> 4;
  const int r16 = lane & 15;

  const int id = blockIdx.x;
  const int b = (id >> 3) & 1;
  const int kh = id & 7;
  const int rest = id >> 4;          // 0..31
  const int p = rest & 7;
  const int qh = rest >> 3;          // 0..3
  const int h = kh * G_ + qh;
  const int qt = (w < 4) ? p : (15 - p);
  const int s0w = qt * 64 + (w & 3) * 16;

  const bf16_t* qp = Qb + ((size_t)(b * NH_ + h) * S_ + s0w + r16) * HD_ + g * 8;
  bf16x8 qf[4];
#pragma unroll
  for (int ks = 0; ks < 4; ++ks) qf[ks] = *(const bf16x8*)(qp + ks * 32);

  const bf16_t* kbase = Kb + (size_t)(b * NKV_ + kh) * L_ * HD_;
  const bf16_t* vbase = Vt + (size_t)(b * NKV_ + kh) * HD_ * L_;

  float m_run = -1e30f;   // running max for q = s0w + r16
  float s_run = 0.f;      // running denom for q = s0w + r16
  f32x4 acc_o[8] = {};

  const float scale = 0.08838834764831845f;  // 1/sqrt(HD)
  const int qpos_base = PAST_ + s0w;
  const int qpos = qpos_base + r16;
  const int ntiles = ((qpos_base + 15) >> 6) + 1;

  for (int t = 0; t < ntiles; ++t) {
    const int lt = t * 64;
    const bool need_mask = (lt + 63) > qpos_base;

    // QK^T swapped: A=K rows(l), B=Q rows(q) -> sc[nt][r] = S[l=lt+nt*16+g*4+r][q=s0w+r16]
    f32x4 sc[4] = {};
#pragma unroll
    for (int nt = 0; nt < 4; ++nt) {
      const bf16_t* kp = kbase + (size_t)(lt + nt * 16 + r16) * HD_ + g * 8;
#pragma unroll
      for (int ks = 0; ks < 4; ++ks) {
        bf16x8 kf = *(const bf16x8*)(kp + ks * 32);
        sc[nt] = __builtin_amdgcn_mfma_f32_16x16x32_bf16(kf, qf[ks], sc[nt], 0, 0, 0);
      }
    }

    // prefetch V (ks2=0 half) while softmax runs
    bf16x8 vf0[8];
#pragma unroll
    for (int d8 = 0; d8 < 8; ++d8)
      vf0[d8] = *(const bf16x8*)(vbase + (size_t)(d8 * 16 + r16) * L_ + lt + g * 8);

    // scale + mask + in-lane max
    float sv[4][4];
    float tmax = -1e30f;
#pragma unroll
    for (int nt = 0; nt < 4; ++nt)
#pragma unroll
      for (int r = 0; r < 4; ++r) {
        float v = sc[nt][r] * scale;
        if (need_mask) {
          int l = lt + nt * 16 + g * 4 + r;
          if (l > qpos) v = -1e30f;
        }
        sv[nt][r] = v;
        tmax = fmaxf(tmax, v);
      }
    tmax = fmaxf(tmax, __shfl_xor(tmax, 16, 64));
    tmax = fmaxf(tmax, __shfl_xor(tmax, 32, 64));

    // defer-max: rescale only when tile max grew past THR=8
    if (!__all(tmax <= m_run + 8.f)) {
      float newm = fmaxf(m_run, tmax);
      float alpha = __expf(m_run - newm);
      m_run = newm;
      s_run *= alpha;
#pragma unroll
      for (int r = 0; r < 4; ++r) {
        float a = __shfl(alpha, g * 4 + r, 64);
#pragma unroll
        for (int d8 = 0; d8 < 8; ++d8) acc_o[d8][r] *= a;
      }
    }

    // P = exp(S - m), row-sum, pack 4 bf16 -> one b64 LDS write per nt
    float psum = 0.f;
#pragma unroll
    for (int nt = 0; nt < 4; ++nt) {
      bf16x4 pk;
#pragma unroll
      for (int r = 0; r < 4; ++r) {
        float pv = __expf(sv[nt][r] - m_run);
        psum += pv;
        pk[r] = (bf16_t)pv;
      }
      *(bf16x4*)&P_lds[w][r16][nt * 16 + g * 4] = pk;
    }
    psum += __shfl_xor(psum, 16, 64);
    psum += __shfl_xor(psum, 32, 64);
    s_run += psum;

    // PV: A=P rows(q), B=Vt rows(d)
#pragma unroll
    for (int ks2 = 0; ks2 < 2; ++ks2) {
      bf16x8 pa = *(const bf16x8*)&P_lds[w][r16][ks2 * 32 + g * 8];
#pragma unroll
      for (int d8 = 0; d8 < 8; ++d8) {
        bf16x8 vf = (ks2 == 0)
            ? vf0[d8]
            : *(const bf16x8*)(vbase + (size_t)(d8 * 16 + r16) * L_ + lt + 32 + g * 8);
        acc_o[d8] = __builtin_amdgcn_mfma_f32_16x16x32_bf16(pa, vf, acc_o[d8], 0, 0, 0);
      }
    }
  }

  float inv[4];
#pragma unroll
  for (int r = 0; r < 4; ++r) inv[r] = 1.f / __shfl(s_run, g * 4 + r, 64);
#pragma unroll
  for (int d8 = 0; d8 < 8; ++d8)
#pragma unroll
    for (int r = 0; r < 4; ++r) {
      int tok = b * S_ + s0w + g * 4 + r;
      int col = h * HD_ + d8 * 16 + r16;
      Ctx[(size_t)tok * HID_ + col] = (bf16_t)(acc_o[d8][r] * inv[r]);
    }
}

// ---------------------------------------------------------------------------
extern "C" void kernel_launch(void* const* d_in, const int* in_sizes, int n_in,
                              void* d_out, int out_size, void* d_ws, size_t ws_size,
                              hipStream_t stream) {
  const float* hidden = (const float*)d_in[0];
  const float* kv_cache = (const float*)d_in[1];
  const float* rope = (const float*)d_in[2];
  const float* Wq = (const float*)d_in[3];
  const float* Wk = (const float*)d_in[4];
  const float* Wv = (const float*)d_in[5];
  const float* Wo = (const float*)d_in[6];
  const int* kv_lut = (const int*)d_in[9];
  float* out = (float*)d_out;

  // workspace layout (bf16 elements)
  bf16_t* Xb = (bf16_t*)d_ws;                      //  2048*4096
  bf16_t* Wcat = Xb + (size_t)2048 * 4096;         //  6144*4096 (B^T: [n][k])
  bf16_t* Wot = Wcat + (size_t)6144 * 4096;        //  4096*4096
  bf16_t* QKVb = Wot + (size_t)4096 * 4096;        //  2048*6144
  bf16_t* Qb = QKVb + (size_t)2048 * 6144;         //  B*NH*S*HD
  bf16_t* Kb = Qb + (size_t)B_ * NH_ * S_ * HD_;   //  B*NKV*L*HD
  bf16_t* Vt = Kb + (size_t)B_ * NKV_ * L_ * HD_;  //  B*NKV*HD*L
  bf16_t* Ctx = Xb;                                //  reuse (Xb dead after GEMM1)

  // 1. converts / transposes
  cvt_bf16x8<<<4096, 256, 0, stream>>>(hidden, Xb);
  transpose_cvt<<<dim3(64, 64), 256, 0, stream>>>(Wq, Wcat, 4096, 4096);
  transpose_cvt<<<dim3(16, 64), 256, 0, stream>>>(Wk, Wcat + (size_t)4096 * 4096, 4096, 1024);
  transpose_cvt<<<dim3(16, 64), 256, 0, stream>>>(Wv, Wcat + (size_t)5120 * 4096, 4096, 1024);
  transpose_cvt<<<dim3(64, 64), 256, 0, stream>>>(Wo, Wot, 4096, 4096);

  // 2. QKV projection
  gemm_bt<true><<<dim3(48, 16), 256, 0, stream>>>(Xb, Wcat, QKVb, NQKV_, HID_);

  // 3. RoPE + KV pack
  rope_pack<<<dim3(2048, 20), 256, 0, stream>>>(QKVb, rope, Qb, Kb);
  past_kv<<<256, 256, 0, stream>>>(kv_cache, kv_lut, Kb, Vt);
  v_pack<<<256, 256, 0, stream>>>(QKVb, Vt);

  // 4. attention
  attn<<<512, 512, 0, stream>>>(Qb, Kb, Vt, Ctx);

  // 5. output projection -> fp32 d_out
  gemm_bt<false><<<dim3(32, 16), 256, 0, stream>>>(Ctx, Wot, out, HID_, HID_);
}

// Round 3
// 417.618 us; speedup vs baseline: 1.8783x; 1.6223x over previous
//
#include <hip/hip_runtime.h>
#include <hip/hip_bf16.h>
#include <cstdint>
#include <cstddef>

// Problem constants (fixed by reference)
#define B_    2
#define S_    1024
#define HID_  4096
#define NH_   32
#define NKV_  8
#define HD_   128
#define G_    4
#define PAST_ 1024
#define L_    2048
#define NQKV_ 6144   // NH*HD + 2*NKV*HD

typedef __bf16 bf16_t;
typedef bf16_t bf16x4 __attribute__((ext_vector_type(4)));
typedef bf16_t bf16x8 __attribute__((ext_vector_type(8)));
typedef float  f32x4  __attribute__((ext_vector_type(4)));

__device__ __forceinline__ void gload_lds16(const bf16_t* g, bf16_t* l) {
  __builtin_amdgcn_global_load_lds(
      (const __attribute__((address_space(1))) void*)g,
      (__attribute__((address_space(3))) void*)l, 16, 0, 0);
}

// ---------------------------------------------------------------------------
// fp32 -> bf16 elementwise convert (8 elems/thread)
// ---------------------------------------------------------------------------
__global__ __launch_bounds__(256) void cvt_bf16x8(const float* __restrict__ src,
                                                  bf16_t* __restrict__ dst) {
  size_t i = ((size_t)blockIdx.x * 256 + threadIdx.x) * 8;
  f32x4 a = *(const f32x4*)(src + i);
  f32x4 b = *(const f32x4*)(src + i + 4);
  bf16x8 o;
#pragma unroll
  for (int j = 0; j < 4; ++j) o[j] = (bf16_t)a[j];
#pragma unroll
  for (int j = 0; j < 4; ++j) o[4 + j] = (bf16_t)b[j];
  *(bf16x8*)(dst + i) = o;
}

// ---------------------------------------------------------------------------
// fp32 [R][C] -> bf16 [C][R] tiled transpose-convert
// ---------------------------------------------------------------------------
__global__ __launch_bounds__(256) void transpose_cvt(const float* __restrict__ src,
                                                     bf16_t* __restrict__ dst,
                                                     int R, int C) {
  __shared__ float T[64][65];
  const int tid = threadIdx.x;
  const int c0 = blockIdx.x * 64;
  const int r0 = blockIdx.y * 64;
#pragma unroll
  for (int i = 0; i < 16; ++i) {
    int idx = i * 256 + tid;
    int lr = idx >> 6, lc = idx & 63;
    T[lr][lc] = src[(size_t)(r0 + lr) * C + c0 + lc];
  }
  __syncthreads();
#pragma unroll
  for (int i = 0; i < 16; ++i) {
    int idx = i * 256 + tid;
    int lr = idx >> 6, lc = idx & 63;
    dst[(size_t)(c0 + lr) * R + r0 + lc] = (bf16_t)T[lc][lr];
  }
}

// ---------------------------------------------------------------------------
// bf16 GEMM, m97 structure: C[M][N] = A[M][K] * Bt[N][K]^T
// 128x128 tile, BK=32, 4 waves (2x2), 4x4 16x16x32 frags per wave
// ---------------------------------------------------------------------------
template <bool OUT_BF16>
__global__ __launch_bounds__(256) void gemm_bt(const bf16_t* __restrict__ A,
                                               const bf16_t* __restrict__ Bt,
                                               void* __restrict__ C, int N, int K) {
  __shared__ bf16_t As[128 * 32];
  __shared__ bf16_t Bs[128 * 32];
  const int tid = threadIdx.x;
  const int lane = tid & 63;
  const int w = tid >> 6;
  const int wm = w >> 1, wn = w & 1;
  const int m0 = blockIdx.y * 128;
  const int n0 = blockIdx.x * 128;
  const int g = lane >> 4;
  const int r16 = lane & 15;

  f32x4 acc[4][4] = {};

  for (int kt = 0; kt < K; kt += 32) {
    __syncthreads();
#pragma unroll
    for (int j = 0; j < 2; ++j) {
      int cbase = (w * 2 + j) * 64;
      int chunk = cbase + lane;
      gload_lds16(A + (size_t)(m0 + (chunk >> 2)) * K + kt + (chunk & 3) * 8,
                  As + cbase * 8);
      gload_lds16(Bt + (size_t)(n0 + (chunk >> 2)) * K + kt + (chunk & 3) * 8,
                  Bs + cbase * 8);
    }
    __syncthreads();
    bf16x8 af[4], bf[4];
#pragma unroll
    for (int i = 0; i < 4; ++i)
      af[i] = *(const bf16x8*)&As[(wm * 64 + i * 16 + r16) * 32 + g * 8];
#pragma unroll
    for (int i = 0; i < 4; ++i)
      bf[i] = *(const bf16x8*)&Bs[(wn * 64 + i * 16 + r16) * 32 + g * 8];
#pragma unroll
    for (int i = 0; i < 4; ++i)
#pragma unroll
      for (int j2 = 0; j2 < 4; ++j2)
        acc[i][j2] = __builtin_amdgcn_mfma_f32_16x16x32_bf16(af[i], bf[j2],
                                                             acc[i][j2], 0, 0, 0);
  }

#pragma unroll
  for (int i = 0; i < 4; ++i)
#pragma unroll
    for (int j2 = 0; j2 < 4; ++j2)
#pragma unroll
      for (int r = 0; r < 4; ++r) {
        int row = m0 + wm * 64 + i * 16 + g * 4 + r;
        int col = n0 + wn * 64 + j2 * 16 + r16;
        if (OUT_BF16)
          ((bf16_t*)C)[(size_t)row * N + col] = (bf16_t)acc[i][j2][r];
        else
          ((float*)C)[(size_t)row * N + col] = acc[i][j2][r];
      }
}

// ---------------------------------------------------------------------------
// RoPE on q,k from QKV buffer; scatter into Qb[B,NH,S,HD], Kb[B,NKV,L,HD] (new part)
// grid (tokens, 20), block 256 (2 heads per block)
// ---------------------------------------------------------------------------
__global__ __launch_bounds__(256) void rope_pack(const bf16_t* __restrict__ QKV,
                                                 const float* __restrict__ rope,
                                                 bf16_t* __restrict__ Qb,
                                                 bf16_t* __restrict__ Kb) {
  const int tok = blockIdx.x;
  const int head = blockIdx.y * 2 + (threadIdx.x >> 7);
  const int d = threadIdx.x & 127;
  const int b = tok >> 10, s = tok & 1023;
  const int pos = PAST_ + s;
  const int off = head < NH_ ? head * HD_ : HID_ + (head - NH_) * HD_;
  const bf16_t* row = QKV + (size_t)tok * NQKV_;
  float x = (float)row[off + d];
  int dp = d < 64 ? d + 64 : d - 64;
  float xp = (float)row[off + dp];
  float c = rope[(size_t)(pos * 2) * HD_ + d];
  float sn = rope[(size_t)(pos * 2 + 1) * HD_ + d];
  float out = d < 64 ? x * c - xp * sn : x * c + xp * sn;
  if (head < NH_)
    Qb[((size_t)(b * NH_ + head) * S_ + s) * HD_ + d] = (bf16_t)out;
  else
    Kb[((size_t)(b * NKV_ + (head - NH_)) * L_ + PAST_ + s) * HD_ + d] = (bf16_t)out;
}

// ---------------------------------------------------------------------------
// Past KV: gather kv_cache[kv_lut] for l<PAST -> Kb direct, Vt transposed
// grid B*NKV*(PAST/64) = 256, block 256
// ---------------------------------------------------------------------------
__global__ __launch_bounds__(256) void past_kv(const float* __restrict__ cache,
                                               const int* __restrict__ kv_lut,
                                               bf16_t* __restrict__ Kb,
                                               bf16_t* __restrict__ Vt) {
  __shared__ bf16_t Vs[128][72];
  const int tid = threadIdx.x;
  const int lt = blockIdx.x & 15;
  const int h = (blockIdx.x >> 4) & 7;
  const int b = blockIdx.x >> 7;
  const int l0 = lt * 64;
#pragma unroll
  for (int i = 0; i < 32; ++i) {
    int idx = i * 256 + tid;
    int l = idx >> 7, d = idx & 127;
    int slot = kv_lut[b * L_ + l0 + l];
    float kv = cache[((size_t)slot * 2 * NKV_ + h) * HD_ + d];
    float vv = cache[(((size_t)slot * 2 + 1) * NKV_ + h) * HD_ + d];
    Kb[((size_t)(b * NKV_ + h) * L_ + l0 + l) * HD_ + d] = (bf16_t)kv;
    Vs[d][l] = (bf16_t)vv;
  }
  __syncthreads();
#pragma unroll
  for (int i = 0; i < 32; ++i) {
    int idx = i * 256 + tid;
    int d = idx >> 6, l = idx & 63;
    Vt[((size_t)(b * NKV_ + h) * HD_ + d) * L_ + l0 + l] = Vs[d][l];
  }
}

// ---------------------------------------------------------------------------
// New-token V: QKV v-part -> Vt transposed (l = PAST+s)
// grid B*NKV*(S/64) = 256, block 256
// ---------------------------------------------------------------------------
__global__ __launch_bounds__(256) void v_pack(const bf16_t* __restrict__ QKV,
                                              bf16_t* __restrict__ Vt) {
  __shared__ bf16_t Vs[128][72];
  const int tid = threadIdx.x;
  const int st = blockIdx.x & 15;
  const int h = (blockIdx.x >> 4) & 7;
  const int b = blockIdx.x >> 7;
  const int s0 = st * 64;
#pragma unroll
  for (int i = 0; i < 32; ++i) {
    int idx = i * 256 + tid;
    int sl = idx >> 7, d = idx & 127;
    Vs[d][sl] = QKV[(size_t)(b * S_ + s0 + sl) * NQKV_ + HID_ + NKV_ * HD_ + h * HD_ + d];
  }
  __syncthreads();
#pragma unroll
  for (int i = 0; i < 32; ++i) {
    int idx = i * 256 + tid;
    int d = idx >> 6, l = idx & 63;
    Vt[((size_t)(b * NKV_ + h) * HD_ + d) * L_ + PAST_ + s0 + l] = Vs[d][l];
  }
}

// ---------------------------------------------------------------------------
// Block-cooperative flash attention.
// Block = (b, h, qc): 128 q-rows, 8 waves x 16 rows; all waves share the same
// l-tile sequence; K (64x128 bf16) and V (128x64 bf16) tiles staged in LDS via
// global_load_lds, double-buffered (2-phase schedule). XOR swizzle (chunk ^=
// row&7) on K/V/P: LDS linear, global source pre-swizzled, reads XOR (m173).
// ntiles = 18 + 2*qc uniform per block; qc pairing (7,0)(6,1).. balances CUs;
// id%8 == kh pins each kh's K/V to one XCD L2.
// ---------------------------------------------------------------------------
__global__ __launch_bounds__(512) void attn(const bf16_t* __restrict__ Qb,
                                            const bf16_t* __restrict__ Kb,
                                            const bf16_t* __restrict__ Vt,
                                            bf16_t* __restrict__ Ctx) {
  // smem: K[2][8192] | V[2][8192] | P[8][1024]   (81920 bytes)
  __shared__ bf16_t smem[40960];

  const int tid = threadIdx.x;
  const int lane = tid & 63;
  const int w = tid >> 6;
  const int g = lane >> 4;
  const int r16 = lane & 15;
  const int rx = r16 & 7;

  const int id = blockIdx.x;
  const int kh = id & 7;
  const int b = (id >> 3) & 1;
  const int qh = (id >> 4) & 3;
  const int grp = id >> 6;                 // 0..7
  const int qc = grp < 4 ? 7 - grp : grp - 4;
  const int h = kh * G_ + qh;

  const int s0w = qc * 128 + w * 16;

  const bf16_t* qp = Qb + ((size_t)(b * NH_ + h) * S_ + s0w + r16) * HD_ + g * 8;
  bf16x8 qf[4];
#pragma unroll
  for (int ks = 0; ks < 4; ++ks) qf[ks] = *(const bf16x8*)(qp + ks * 32);

  const bf16_t* kbase = Kb + (size_t)(b * NKV_ + kh) * L_ * HD_;
  const bf16_t* vbase = Vt + (size_t)(b * NKV_ + kh) * HD_ * L_;

  // staging indices (per thread, fixed): 2 K chunks + 2 V chunks of 16B
  const int slot0 = w * 2;
  const int kl0 = slot0 * 4 + (lane >> 4);       // K tile row, rep 0
  const int kc0 = (lane & 15) ^ (kl0 & 7);       // swizzled source chunk
  const int kl1 = kl0 + 4;
  const int kc1 = (lane & 15) ^ (kl1 & 7);
  const int vd0 = slot0 * 8 + (lane >> 3);       // V tile row (d), rep 0
  const int vc0 = (lane & 7) ^ (vd0 & 7);
  const int vd1 = vd0 + 8;
  const int vc1 = (lane & 7) ^ (vd1 & 7);

  float m_run = -1e30f;   // running max for q = s0w + r16
  float s_run = 0.f;      // running denom
  f32x4 acc_o[8] = {};

  const float scale = 0.08838834764831845f;  // 1/sqrt(HD)
  const int qpos_base = PAST_ + s0w;
  const int qpos = qpos_base + r16;
  const int nt_ = 18 + 2 * qc;

  // prologue: stage tile 0 into buf 0
  {
    bf16_t* Kd = smem;
    bf16_t* Vd = smem + 16384;
    gload_lds16(kbase + (size_t)kl0 * HD_ + kc0 * 8, Kd + slot0 * 512);
    gload_lds16(kbase + (size_t)kl1 * HD_ + kc1 * 8, Kd + (slot0 + 1) * 512);
    gload_lds16(vbase + (size_t)vd0 * L_ + vc0 * 8, Vd + slot0 * 512);
    gload_lds16(vbase + (size_t)vd1 * L_ + vc1 * 8, Vd + (slot0 + 1) * 512);
  }
  __syncthreads();

  for (int t = 0; t < nt_; ++t) {
    const int cur = t & 1;
    const int lt = t * 64;

    // stage t+1 into the other buffer (overlaps with compute below)
    if (t + 1 < nt_) {
      const int ltn = lt + 64;
      bf16_t* Kd = smem + (cur ^ 1) * 8192;
      bf16_t* Vd = smem + 16384 + (cur ^ 1) * 8192;
      gload_lds16(kbase + (size_t)(ltn + kl0) * HD_ + kc0 * 8, Kd + slot0 * 512);
      gload_lds16(kbase + (size_t)(ltn + kl1) * HD_ + kc1 * 8, Kd + (slot0 + 1) * 512);
      gload_lds16(vbase + (size_t)vd0 * L_ + ltn + vc0 * 8, Vd + slot0 * 512);
      gload_lds16(vbase + (size_t)vd1 * L_ + ltn + vc1 * 8, Vd + (slot0 + 1) * 512);
    }

    const bf16_t* Kc = smem + cur * 8192;
    const bf16_t* Vc = smem + 16384 + cur * 8192;
    bf16_t* Pw = smem + 32768 + w * 1024;

    // QK^T swapped: sc[nt][r] = S[l = lt+nt*16+g*4+r][q = s0w+r16]
    f32x4 sc[4] = {};
#pragma unroll
    for (int nt = 0; nt < 4; ++nt) {
#pragma unroll
      for (int ks = 0; ks < 4; ++ks) {
        bf16x8 kf = *(const bf16x8*)&Kc[(nt * 16 + r16) * 128 + (((ks * 4 + g) ^ rx) << 3)];
        sc[nt] = __builtin_amdgcn_mfma_f32_16x16x32_bf16(kf, qf[ks], sc[nt], 0, 0, 0);
      }
    }

    // scale + mask + in-lane max
    const bool need_mask = (lt + 63) > qpos_base;
    float sv[4][4];
    float tmax = -1e30f;
#pragma unroll
    for (int nt = 0; nt < 4; ++nt)
#pragma unroll
      for (int r = 0; r < 4; ++r) {
        float v = sc[nt][r] * scale;
        if (need_mask) {
          int l = lt + nt * 16 + g * 4 + r;
          if (l > qpos) v = -1e30f;
        }
        sv[nt][r] = v;
        tmax = fmaxf(tmax, v);
      }
    tmax = fmaxf(tmax, __shfl_xor(tmax, 16, 64));
    tmax = fmaxf(tmax, __shfl_xor(tmax, 32, 64));

    // defer-max (T13, THR=8)
    if (!__all(tmax <= m_run + 8.f)) {
      float newm = fmaxf(m_run, tmax);
      float alpha = __expf(m_run - newm);
      m_run = newm;
      s_run *= alpha;
#pragma unroll
      for (int r = 0; r < 4; ++r) {
        float a = __shfl(alpha, g * 4 + r, 64);
#pragma unroll
        for (int d8 = 0; d8 < 8; ++d8) acc_o[d8][r] *= a;
      }
    }

    // P = exp(S - m), row-sum; pack 4 bf16 -> one b64 swizzled LDS write per nt
    float psum = 0.f;
#pragma unroll
    for (int nt = 0; nt < 4; ++nt) {
      bf16x4 pk;
#pragma unroll
      for (int r = 0; r < 4; ++r) {
        float pv = __expf(sv[nt][r] - m_run);
        psum += pv;
        pk[r] = (bf16_t)pv;
      }
      *(bf16x4*)&Pw[r16 * 64 + (((nt * 2 + (g >> 1)) ^ rx) << 3) + (g & 1) * 4] = pk;
    }
    psum += __shfl_xor(psum, 16, 64);
    psum += __shfl_xor(psum, 32, 64);
    s_run += psum;

    // PV: A = P rows(q), B = V rows(d), both from swizzled LDS
#pragma unroll
    for (int ks2 = 0; ks2 < 2; ++ks2) {
      bf16x8 pa = *(const bf16x8*)&Pw[r16 * 64 + (((ks2 * 4 + g) ^ rx) << 3)];
#pragma unroll
      for (int d8 = 0; d8 < 8; ++d8) {
        bf16x8 vf = *(const bf16x8*)&Vc[(d8 * 16 + r16) * 64 + (((ks2 * 4 + g) ^ rx) << 3)];
        acc_o[d8] = __builtin_amdgcn_mfma_f32_16x16x32_bf16(pa, vf, acc_o[d8], 0, 0, 0);
      }
    }

    __syncthreads();  // drains vmcnt (stage t+1 done) + all waves done with cur
  }

  float inv[4];
#pragma unroll
  for (int r = 0; r < 4; ++r) inv[r] = 1.f / __shfl(s_run, g * 4 + r, 64);
#pragma unroll
  for (int d8 = 0; d8 < 8; ++d8)
#pragma unroll
    for (int r = 0; r < 4; ++r) {
      int tok = b * S_ + s0w + g * 4 + r;
      int col = h * HD_ + d8 * 16 + r16;
      Ctx[(size_t)tok * HID_ + col] = (bf16_t)(acc_o[d8][r] * inv[r]);
    }
}

// ---------------------------------------------------------------------------
extern "C" void kernel_launch(void* const* d_in, const int* in_sizes, int n_in,
                              void* d_out, int out_size, void* d_ws, size_t ws_size,
                              hipStream_t stream) {
  const float* hidden = (const float*)d_in[0];
  const float* kv_cache = (const float*)d_in[1];
  const float* rope = (const float*)d_in[2];
  const float* Wq = (const float*)d_in[3];
  const float* Wk = (const float*)d_in[4];
  const float* Wv = (const float*)d_in[5];
  const float* Wo = (const float*)d_in[6];
  const int* kv_lut = (const int*)d_in[9];
  float* out = (float*)d_out;

  // workspace layout (bf16 elements)
  bf16_t* Xb = (bf16_t*)d_ws;                      //  2048*4096
  bf16_t* Wcat = Xb + (size_t)2048 * 4096;         //  6144*4096 (B^T: [n][k])
  bf16_t* Wot = Wcat + (size_t)6144 * 4096;        //  4096*4096
  bf16_t* QKVb = Wot + (size_t)4096 * 4096;        //  2048*6144
  bf16_t* Qb = QKVb + (size_t)2048 * 6144;         //  B*NH*S*HD
  bf16_t* Kb = Qb + (size_t)B_ * NH_ * S_ * HD_;   //  B*NKV*L*HD
  bf16_t* Vt = Kb + (size_t)B_ * NKV_ * L_ * HD_;  //  B*NKV*HD*L
  bf16_t* Ctx = Xb;                                //  reuse (Xb dead after GEMM1)

  // 1. converts / transposes
  cvt_bf16x8<<<4096, 256, 0, stream>>>(hidden, Xb);
  transpose_cvt<<<dim3(64, 64), 256, 0, stream>>>(Wq, Wcat, 4096, 4096);
  transpose_cvt<<<dim3(16, 64), 256, 0, stream>>>(Wk, Wcat + (size_t)4096 * 4096, 4096, 1024);
  transpose_cvt<<<dim3(16, 64), 256, 0, stream>>>(Wv, Wcat + (size_t)5120 * 4096, 4096, 1024);
  transpose_cvt<<<dim3(64, 64), 256, 0, stream>>>(Wo, Wot, 4096, 4096);

  // 2. QKV projection
  gemm_bt<true><<<dim3(48, 16), 256, 0, stream>>>(Xb, Wcat, QKVb, NQKV_, HID_);

  // 3. RoPE + KV pack
  rope_pack<<<dim3(2048, 20), 256, 0, stream>>>(QKVb, rope, Qb, Kb);
  past_kv<<<256, 256, 0, stream>>>(kv_cache, kv_lut, Kb, Vt);
  v_pack<<<256, 256, 0, stream>>>(QKVb, Vt);

  // 4. attention
  attn<<<512, 512, 0, stream>>>(Qb, Kb, Vt, Ctx);

  // 5. output projection -> fp32 d_out
  gemm_bt<false><<<dim3(32, 16), 256, 0, stream>>>(Ctx, Wot, out, HID_, HID_);
}

// Round 4
// 351.526 us; speedup vs baseline: 2.2315x; 1.1880x over previous
//
#include <hip/hip_runtime.h>
#include <hip/hip_bf16.h>
#include <cstdint>
#include <cstddef>

// Problem constants (fixed by reference)
#define B_    2
#define S_    1024
#define HID_  4096
#define NH_   32
#define NKV_  8
#define HD_   128
#define G_    4
#define PAST_ 1024
#define L_    2048
#define NQKV_ 6144   // NH*HD + 2*NKV*HD

typedef __bf16 bf16_t;
typedef bf16_t bf16x4 __attribute__((ext_vector_type(4)));
typedef bf16_t bf16x8 __attribute__((ext_vector_type(8)));
typedef float  f32x4  __attribute__((ext_vector_type(4)));

__device__ __forceinline__ void gload_lds16(const bf16_t* g, bf16_t* l) {
  __builtin_amdgcn_global_load_lds(
      (const __attribute__((address_space(1))) void*)g,
      (__attribute__((address_space(3))) void*)l, 16, 0, 0);
}

// ---------------------------------------------------------------------------
// fp32 -> bf16 elementwise convert (8 elems/thread)
// ---------------------------------------------------------------------------
__global__ __launch_bounds__(256) void cvt_bf16x8(const float* __restrict__ src,
                                                  bf16_t* __restrict__ dst) {
  size_t i = ((size_t)blockIdx.x * 256 + threadIdx.x) * 8;
  f32x4 a = *(const f32x4*)(src + i);
  f32x4 b = *(const f32x4*)(src + i + 4);
  bf16x8 o;
#pragma unroll
  for (int j = 0; j < 4; ++j) o[j] = (bf16_t)a[j];
#pragma unroll
  for (int j = 0; j < 4; ++j) o[4 + j] = (bf16_t)b[j];
  *(bf16x8*)(dst + i) = o;
}

// ---------------------------------------------------------------------------
// fp32 [R][C] -> bf16 [C][R] tiled transpose-convert
// ---------------------------------------------------------------------------
__global__ __launch_bounds__(256) void transpose_cvt(const float* __restrict__ src,
                                                     bf16_t* __restrict__ dst,
                                                     int R, int C) {
  __shared__ float T[64][65];
  const int tid = threadIdx.x;
  const int c0 = blockIdx.x * 64;
  const int r0 = blockIdx.y * 64;
#pragma unroll
  for (int i = 0; i < 16; ++i) {
    int idx = i * 256 + tid;
    int lr = idx >> 6, lc = idx & 63;
    T[lr][lc] = src[(size_t)(r0 + lr) * C + c0 + lc];
  }
  __syncthreads();
#pragma unroll
  for (int i = 0; i < 16; ++i) {
    int idx = i * 256 + tid;
    int lr = idx >> 6, lc = idx & 63;
    dst[(size_t)(c0 + lr) * R + r0 + lc] = (bf16_t)T[lc][lr];
  }
}

// ---------------------------------------------------------------------------
// Deep-pipelined bf16 GEMM: C[M][N] = A[M][K] * Bt[N][K]^T
// BM=256, BN template (192 or 128), BK=64 as two 32-wide k-slabs.
// 512 threads = 8 waves (2 M-halves x 4 N-quarters); per-wave out 128 x BN/4.
// 2 K-tile LDS double buffer; per phase: ds_read frags -> issue next-tile slab
// staging (other buffer) -> MFMA -> counted vmcnt (never 0) -> raw s_barrier.
// XOR swizzle byte^=((byte>>9)&1)<<5 on LDS tiles; global source pre-swizzled
// (LDS dest linear for global_load_lds). Bijective XCD swizzle on 256 blocks.
// ---------------------------------------------------------------------------
template <int BN, bool OUT_BF16>
__global__ __launch_bounds__(512) void gemm8(const bf16_t* __restrict__ A,
                                             const bf16_t* __restrict__ Bt,
                                             void* __restrict__ C, int N, int K) {
  constexpr int BSLAB = BN * 32;          // elems per B slab
  constexpr int BUFE = 16384 + 2 * BSLAB; // elems per K-tile buffer
  constexpr int NF = BN / 64;             // B frags per wave (3 or 2)
  constexpr int WN = BN / 4;              // per-wave N span
  constexpr int BCH = BN * 4;             // 16B chunks per B slab
  __shared__ bf16_t sm[2 * BUFE];

  const int tid = threadIdx.x;
  const int lane = tid & 63;
  const int w = tid >> 6;
  const int wm = w >> 2, wn = w & 3;
  const int g = lane >> 4;
  const int r16 = lane & 15;

  // bijective XCD swizzle: 256 blocks, 32 per XCD, contiguous tx-range per XCD
  const int flat = blockIdx.y * 32 + blockIdx.x;
  const int xcd = flat & 7;
  const int i2 = flat >> 3;
  const int tx = xcd * 4 + (i2 & 3);
  const int ty = i2 >> 2;
  const int m0 = ty * 256;
  const int n0 = tx * BN;

  const int NT = K >> 6;

  f32x4 acc[8][NF] = {};

  // ---- staging helpers (issue only; wave-uniform LDS dest, swizzled src) ----
  auto stageA = [&](int T, int j) {
    bf16_t* base = sm + (T & 1) * BUFE + j * 8192;
#pragma unroll
    for (int cj = 0; cj < 2; ++cj) {
      int c = (w * 2 + cj) * 64 + lane;
      int p = c * 16;
      int l = p ^ (((p >> 9) & 1) << 5);
      int row = l >> 6, colb = l & 63;
      gload_lds16(A + (size_t)(m0 + row) * K + T * 64 + j * 32 + (colb >> 1),
                  base + (w * 2 + cj) * 512);
    }
  };
  auto stageB = [&](int T, int j) {
    bf16_t* base = sm + (T & 1) * BUFE + 16384 + j * BSLAB;
#pragma unroll
    for (int cj = 0; cj < (BCH + 511) / 512; ++cj) {
      int cbase = cj * 512 + w * 64;
      if (cbase < BCH) {
        int c = cbase + lane;
        int p = c * 16;
        int l = p ^ (((p >> 9) & 1) << 5);
        int row = l >> 6, colb = l & 63;
        gload_lds16(Bt + (size_t)(n0 + row) * K + T * 64 + j * 32 + (colb >> 1),
                    base + cbase * 8);
      }
    }
  };
  // per-wave issues per phase: A=2, B = 2 (BN=192, w<4) or 1
  auto waitbar = [&]() {
    if (BN == 192) {
      if (w < 4) asm volatile("s_waitcnt vmcnt(4)" ::: "memory");
      else       asm volatile("s_waitcnt vmcnt(3)" ::: "memory");
    } else {
      asm volatile("s_waitcnt vmcnt(3)" ::: "memory");
    }
    asm volatile("s_barrier" ::: "memory");
  };

  // prologue: stage tile 0 (slab 0 then slab 1); wait slab0; barrier
  stageA(0, 0); stageB(0, 0);
  stageA(0, 1); stageB(0, 1);
  waitbar();

#pragma unroll 2
  for (int T = 0; T < NT; ++T) {
    const bf16_t* abuf = sm + (T & 1) * BUFE;
    const bf16_t* bbuf = abuf + 16384;
#pragma unroll
    for (int j = 0; j < 2; ++j) {
      const bf16_t* as = abuf + j * 8192;
      const bf16_t* bs = bbuf + j * BSLAB;
      bf16x8 af[8];
      bf16x8 bfr[NF];
#pragma unroll
      for (int m = 0; m < 8; ++m) {
        int a = (wm * 128 + m * 16 + r16) * 64 + g * 16;
        a ^= ((a >> 9) & 1) << 5;
        af[m] = *(const bf16x8*)((const char*)as + a);
      }
#pragma unroll
      for (int n = 0; n < NF; ++n) {
        int a = (wn * WN + n * 16 + r16) * 64 + g * 16;
        a ^= ((a >> 9) & 1) << 5;
        bfr[n] = *(const bf16x8*)((const char*)bs + a);
      }
      if (T + 1 < NT) { stageA(T + 1, j); stageB(T + 1, j); }
      __builtin_amdgcn_s_setprio(1);
#pragma unroll
      for (int m = 0; m < 8; ++m)
#pragma unroll
        for (int n = 0; n < NF; ++n)
          acc[m][n] = __builtin_amdgcn_mfma_f32_16x16x32_bf16(af[m], bfr[n],
                                                              acc[m][n], 0, 0, 0);
      __builtin_amdgcn_s_setprio(0);
      waitbar();
    }
  }

#pragma unroll
  for (int m = 0; m < 8; ++m)
#pragma unroll
    for (int n = 0; n < NF; ++n)
#pragma unroll
      for (int r = 0; r < 4; ++r) {
        int row = m0 + wm * 128 + m * 16 + g * 4 + r;
        int col = n0 + wn * WN + n * 16 + r16;
        if (OUT_BF16)
          ((bf16_t*)C)[(size_t)row * N + col] = (bf16_t)acc[m][n][r];
        else
          ((float*)C)[(size_t)row * N + col] = acc[m][n][r];
      }
}

// ---------------------------------------------------------------------------
// RoPE on q,k from QKV buffer; scatter into Qb[B,NH,S,HD], Kb[B,NKV,L,HD]
// grid (tokens, 20), block 256 (2 heads per block)
// ---------------------------------------------------------------------------
__global__ __launch_bounds__(256) void rope_pack(const bf16_t* __restrict__ QKV,
                                                 const float* __restrict__ rope,
                                                 bf16_t* __restrict__ Qb,
                                                 bf16_t* __restrict__ Kb) {
  const int tok = blockIdx.x;
  const int head = blockIdx.y * 2 + (threadIdx.x >> 7);
  const int d = threadIdx.x & 127;
  const int b = tok >> 10, s = tok & 1023;
  const int pos = PAST_ + s;
  const int off = head < NH_ ? head * HD_ : HID_ + (head - NH_) * HD_;
  const bf16_t* row = QKV + (size_t)tok * NQKV_;
  float x = (float)row[off + d];
  int dp = d < 64 ? d + 64 : d - 64;
  float xp = (float)row[off + dp];
  float c = rope[(size_t)(pos * 2) * HD_ + d];
  float sn = rope[(size_t)(pos * 2 + 1) * HD_ + d];
  float out = d < 64 ? x * c - xp * sn : x * c + xp * sn;
  if (head < NH_)
    Qb[((size_t)(b * NH_ + head) * S_ + s) * HD_ + d] = (bf16_t)out;
  else
    Kb[((size_t)(b * NKV_ + (head - NH_)) * L_ + PAST_ + s) * HD_ + d] = (bf16_t)out;
}

// ---------------------------------------------------------------------------
// Past KV: gather kv_cache[kv_lut] for l<PAST -> Kb direct, Vt transposed
// grid B*NKV*(PAST/64) = 256, block 256
// ---------------------------------------------------------------------------
__global__ __launch_bounds__(256) void past_kv(const float* __restrict__ cache,
                                               const int* __restrict__ kv_lut,
                                               bf16_t* __restrict__ Kb,
                                               bf16_t* __restrict__ Vt) {
  __shared__ bf16_t Vs[128][72];
  const int tid = threadIdx.x;
  const int lt = blockIdx.x & 15;
  const int h = (blockIdx.x >> 4) & 7;
  const int b = blockIdx.x >> 7;
  const int l0 = lt * 64;
#pragma unroll
  for (int i = 0; i < 32; ++i) {
    int idx = i * 256 + tid;
    int l = idx >> 7, d = idx & 127;
    int slot = kv_lut[b * L_ + l0 + l];
    float kv = cache[((size_t)slot * 2 * NKV_ + h) * HD_ + d];
    float vv = cache[(((size_t)slot * 2 + 1) * NKV_ + h) * HD_ + d];
    Kb[((size_t)(b * NKV_ + h) * L_ + l0 + l) * HD_ + d] = (bf16_t)kv;
    Vs[d][l] = (bf16_t)vv;
  }
  __syncthreads();
#pragma unroll
  for (int i = 0; i < 32; ++i) {
    int idx = i * 256 + tid;
    int d = idx >> 6, l = idx & 63;
    Vt[((size_t)(b * NKV_ + h) * HD_ + d) * L_ + l0 + l] = Vs[d][l];
  }
}

// ---------------------------------------------------------------------------
// New-token V: QKV v-part -> Vt transposed (l = PAST+s)
// grid B*NKV*(S/64) = 256, block 256
// ---------------------------------------------------------------------------
__global__ __launch_bounds__(256) void v_pack(const bf16_t* __restrict__ QKV,
                                              bf16_t* __restrict__ Vt) {
  __shared__ bf16_t Vs[128][72];
  const int tid = threadIdx.x;
  const int st = blockIdx.x & 15;
  const int h = (blockIdx.x >> 4) & 7;
  const int b = blockIdx.x >> 7;
  const int s0 = st * 64;
#pragma unroll
  for (int i = 0; i < 32; ++i) {
    int idx = i * 256 + tid;
    int sl = idx >> 7, d = idx & 127;
    Vs[d][sl] = QKV[(size_t)(b * S_ + s0 + sl) * NQKV_ + HID_ + NKV_ * HD_ + h * HD_ + d];
  }
  __syncthreads();
#pragma unroll
  for (int i = 0; i < 32; ++i) {
    int idx = i * 256 + tid;
    int d = idx >> 6, l = idx & 63;
    Vt[((size_t)(b * NKV_ + h) * HD_ + d) * L_ + PAST_ + s0 + l] = Vs[d][l];
  }
}

// ---------------------------------------------------------------------------
// Block-cooperative flash attention (unchanged from R3).
// ---------------------------------------------------------------------------
__global__ __launch_bounds__(512) void attn(const bf16_t* __restrict__ Qb,
                                            const bf16_t* __restrict__ Kb,
                                            const bf16_t* __restrict__ Vt,
                                            bf16_t* __restrict__ Ctx) {
  // smem: K[2][8192] | V[2][8192] | P[8][1024]   (81920 bytes)
  __shared__ bf16_t smem[40960];

  const int tid = threadIdx.x;
  const int lane = tid & 63;
  const int w = tid >> 6;
  const int g = lane >> 4;
  const int r16 = lane & 15;
  const int rx = r16 & 7;

  const int id = blockIdx.x;
  const int kh = id & 7;
  const int b = (id >> 3) & 1;
  const int qh = (id >> 4) & 3;
  const int grp = id >> 6;                 // 0..7
  const int qc = grp < 4 ? 7 - grp : grp - 4;
  const int h = kh * G_ + qh;

  const int s0w = qc * 128 + w * 16;

  const bf16_t* qp = Qb + ((size_t)(b * NH_ + h) * S_ + s0w + r16) * HD_ + g * 8;
  bf16x8 qf[4];
#pragma unroll
  for (int ks = 0; ks < 4; ++ks) qf[ks] = *(const bf16x8*)(qp + ks * 32);

  const bf16_t* kbase = Kb + (size_t)(b * NKV_ + kh) * L_ * HD_;
  const bf16_t* vbase = Vt + (size_t)(b * NKV_ + kh) * HD_ * L_;

  // staging indices (per thread, fixed): 2 K chunks + 2 V chunks of 16B
  const int slot0 = w * 2;
  const int kl0 = slot0 * 4 + (lane >> 4);       // K tile row, rep 0
  const int kc0 = (lane & 15) ^ (kl0 & 7);       // swizzled source chunk
  const int kl1 = kl0 + 4;
  const int kc1 = (lane & 15) ^ (kl1 & 7);
  const int vd0 = slot0 * 8 + (lane >> 3);       // V tile row (d), rep 0
  const int vc0 = (lane & 7) ^ (vd0 & 7);
  const int vd1 = vd0 + 8;
  const int vc1 = (lane & 7) ^ (vd1 & 7);

  float m_run = -1e30f;   // running max for q = s0w + r16
  float s_run = 0.f;      // running denom
  f32x4 acc_o[8] = {};

  const float scale = 0.08838834764831845f;  // 1/sqrt(HD)
  const int qpos_base = PAST_ + s0w;
  const int qpos = qpos_base + r16;
  const int nt_ = 18 + 2 * qc;

  // prologue: stage tile 0 into buf 0
  {
    bf16_t* Kd = smem;
    bf16_t* Vd = smem + 16384;
    gload_lds16(kbase + (size_t)kl0 * HD_ + kc0 * 8, Kd + slot0 * 512);
    gload_lds16(kbase + (size_t)kl1 * HD_ + kc1 * 8, Kd + (slot0 + 1) * 512);
    gload_lds16(vbase + (size_t)vd0 * L_ + vc0 * 8, Vd + slot0 * 512);
    gload_lds16(vbase + (size_t)vd1 * L_ + vc1 * 8, Vd + (slot0 + 1) * 512);
  }
  __syncthreads();

  for (int t = 0; t < nt_; ++t) {
    const int cur = t & 1;
    const int lt = t * 64;

    // stage t+1 into the other buffer (overlaps with compute below)
    if (t + 1 < nt_) {
      const int ltn = lt + 64;
      bf16_t* Kd = smem + (cur ^ 1) * 8192;
      bf16_t* Vd = smem + 16384 + (cur ^ 1) * 8192;
      gload_lds16(kbase + (size_t)(ltn + kl0) * HD_ + kc0 * 8, Kd + slot0 * 512);
      gload_lds16(kbase + (size_t)(ltn + kl1) * HD_ + kc1 * 8, Kd + (slot0 + 1) * 512);
      gload_lds16(vbase + (size_t)vd0 * L_ + ltn + vc0 * 8, Vd + slot0 * 512);
      gload_lds16(vbase + (size_t)vd1 * L_ + ltn + vc1 * 8, Vd + (slot0 + 1) * 512);
    }

    const bf16_t* Kc = smem + cur * 8192;
    const bf16_t* Vc = smem + 16384 + cur * 8192;
    bf16_t* Pw = smem + 32768 + w * 1024;

    // QK^T swapped: sc[nt][r] = S[l = lt+nt*16+g*4+r][q = s0w+r16]
    f32x4 sc[4] = {};
#pragma unroll
    for (int nt = 0; nt < 4; ++nt) {
#pragma unroll
      for (int ks = 0; ks < 4; ++ks) {
        bf16x8 kf = *(const bf16x8*)&Kc[(nt * 16 + r16) * 128 + (((ks * 4 + g) ^ rx) << 3)];
        sc[nt] = __builtin_amdgcn_mfma_f32_16x16x32_bf16(kf, qf[ks], sc[nt], 0, 0, 0);
      }
    }

    // scale + mask + in-lane max
    const bool need_mask = (lt + 63) > qpos_base;
    float sv[4][4];
    float tmax = -1e30f;
#pragma unroll
    for (int nt = 0; nt < 4; ++nt)
#pragma unroll
      for (int r = 0; r < 4; ++r) {
        float v = sc[nt][r] * scale;
        if (need_mask) {
          int l = lt + nt * 16 + g * 4 + r;
          if (l > qpos) v = -1e30f;
        }
        sv[nt][r] = v;
        tmax = fmaxf(tmax, v);
      }
    tmax = fmaxf(tmax, __shfl_xor(tmax, 16, 64));
    tmax = fmaxf(tmax, __shfl_xor(tmax, 32, 64));

    // defer-max (T13, THR=8)
    if (!__all(tmax <= m_run + 8.f)) {
      float newm = fmaxf(m_run, tmax);
      float alpha = __expf(m_run - newm);
      m_run = newm;
      s_run *= alpha;
#pragma unroll
      for (int r = 0; r < 4; ++r) {
        float a = __shfl(alpha, g * 4 + r, 64);
#pragma unroll
        for (int d8 = 0; d8 < 8; ++d8) acc_o[d8][r] *= a;
      }
    }

    // P = exp(S - m), row-sum; pack 4 bf16 -> one b64 swizzled LDS write per nt
    float psum = 0.f;
#pragma unroll
    for (int nt = 0; nt < 4; ++nt) {
      bf16x4 pk;
#pragma unroll
      for (int r = 0; r < 4; ++r) {
        float pv = __expf(sv[nt][r] - m_run);
        psum += pv;
        pk[r] = (bf16_t)pv;
      }
      *(bf16x4*)&Pw[r16 * 64 + (((nt * 2 + (g >> 1)) ^ rx) << 3) + (g & 1) * 4] = pk;
    }
    psum += __shfl_xor(psum, 16, 64);
    psum += __shfl_xor(psum, 32, 64);
    s_run += psum;

    // PV: A = P rows(q), B = V rows(d), both from swizzled LDS
#pragma unroll
    for (int ks2 = 0; ks2 < 2; ++ks2) {
      bf16x8 pa = *(const bf16x8*)&Pw[r16 * 64 + (((ks2 * 4 + g) ^ rx) << 3)];
#pragma unroll
      for (int d8 = 0; d8 < 8; ++d8) {
        bf16x8 vf = *(const bf16x8*)&Vc[(d8 * 16 + r16) * 64 + (((ks2 * 4 + g) ^ rx) << 3)];
        acc_o[d8] = __builtin_amdgcn_mfma_f32_16x16x32_bf16(pa, vf, acc_o[d8], 0, 0, 0);
      }
    }

    __syncthreads();  // drains vmcnt (stage t+1 done) + all waves done with cur
  }

  float inv[4];
#pragma unroll
  for (int r = 0; r < 4; ++r) inv[r] = 1.f / __shfl(s_run, g * 4 + r, 64);
#pragma unroll
  for (int d8 = 0; d8 < 8; ++d8)
#pragma unroll
    for (int r = 0; r < 4; ++r) {
      int tok = b * S_ + s0w + g * 4 + r;
      int col = h * HD_ + d8 * 16 + r16;
      Ctx[(size_t)tok * HID_ + col] = (bf16_t)(acc_o[d8][r] * inv[r]);
    }
}

// ---------------------------------------------------------------------------
extern "C" void kernel_launch(void* const* d_in, const int* in_sizes, int n_in,
                              void* d_out, int out_size, void* d_ws, size_t ws_size,
                              hipStream_t stream) {
  const float* hidden = (const float*)d_in[0];
  const float* kv_cache = (const float*)d_in[1];
  const float* rope = (const float*)d_in[2];
  const float* Wq = (const float*)d_in[3];
  const float* Wk = (const float*)d_in[4];
  const float* Wv = (const float*)d_in[5];
  const float* Wo = (const float*)d_in[6];
  const int* kv_lut = (const int*)d_in[9];
  float* out = (float*)d_out;

  // workspace layout (bf16 elements)
  bf16_t* Xb = (bf16_t*)d_ws;                      //  2048*4096
  bf16_t* Wcat = Xb + (size_t)2048 * 4096;         //  6144*4096 (B^T: [n][k])
  bf16_t* Wot = Wcat + (size_t)6144 * 4096;        //  4096*4096
  bf16_t* QKVb = Wot + (size_t)4096 * 4096;        //  2048*6144
  bf16_t* Qb = QKVb + (size_t)2048 * 6144;         //  B*NH*S*HD
  bf16_t* Kb = Qb + (size_t)B_ * NH_ * S_ * HD_;   //  B*NKV*L*HD
  bf16_t* Vt = Kb + (size_t)B_ * NKV_ * L_ * HD_;  //  B*NKV*HD*L
  bf16_t* Ctx = Xb;                                //  reuse (Xb dead after GEMM1)

  // 1. converts / transposes
  cvt_bf16x8<<<4096, 256, 0, stream>>>(hidden, Xb);
  transpose_cvt<<<dim3(64, 64), 256, 0, stream>>>(Wq, Wcat, 4096, 4096);
  transpose_cvt<<<dim3(16, 64), 256, 0, stream>>>(Wk, Wcat + (size_t)4096 * 4096, 4096, 1024);
  transpose_cvt<<<dim3(16, 64), 256, 0, stream>>>(Wv, Wcat + (size_t)5120 * 4096, 4096, 1024);
  transpose_cvt<<<dim3(64, 64), 256, 0, stream>>>(Wo, Wot, 4096, 4096);

  // 2. QKV projection (BM=256, BN=192 -> 32x8 = 256 blocks, 1/CU)
  gemm8<192, true><<<dim3(32, 8), 512, 0, stream>>>(Xb, Wcat, QKVb, NQKV_, HID_);

  // 3. RoPE + KV pack
  rope_pack<<<dim3(2048, 20), 256, 0, stream>>>(QKVb, rope, Qb, Kb);
  past_kv<<<256, 256, 0, stream>>>(kv_cache, kv_lut, Kb, Vt);
  v_pack<<<256, 256, 0, stream>>>(QKVb, Vt);

  // 4. attention
  attn<<<512, 512, 0, stream>>>(Qb, Kb, Vt, Ctx);

  // 5. output projection -> fp32 d_out (BM=256, BN=128 -> 32x8 = 256 blocks)
  gemm8<128, false><<<dim3(32, 8), 512, 0, stream>>>(Ctx, Wot, out, HID_, HID_);
}

// Round 5
// 350.050 us; speedup vs baseline: 2.2409x; 1.0042x over previous
//
#include <hip/hip_runtime.h>
#include <hip/hip_bf16.h>
#include <cstdint>
#include <cstddef>

// Problem constants (fixed by reference)
#define B_    2
#define S_    1024
#define HID_  4096
#define NH_   32
#define NKV_  8
#define HD_   128
#define G_    4
#define PAST_ 1024
#define L_    2048
#define NQKV_ 6144   // NH*HD + 2*NKV*HD

typedef __bf16 bf16_t;
typedef bf16_t bf16x4 __attribute__((ext_vector_type(4)));
typedef bf16_t bf16x8 __attribute__((ext_vector_type(8)));
typedef float  f32x4  __attribute__((ext_vector_type(4)));

__device__ __forceinline__ void gload_lds16(const bf16_t* g, bf16_t* l) {
  __builtin_amdgcn_global_load_lds(
      (const __attribute__((address_space(1))) void*)g,
      (__attribute__((address_space(3))) void*)l, 16, 0, 0);
}

// ---------------------------------------------------------------------------
// fp32 -> bf16 elementwise convert (8 elems/thread)
// ---------------------------------------------------------------------------
__global__ __launch_bounds__(256) void cvt_bf16x8(const float* __restrict__ src,
                                                  bf16_t* __restrict__ dst) {
  size_t i = ((size_t)blockIdx.x * 256 + threadIdx.x) * 8;
  f32x4 a = *(const f32x4*)(src + i);
  f32x4 b = *(const f32x4*)(src + i + 4);
  bf16x8 o;
#pragma unroll
  for (int j = 0; j < 4; ++j) o[j] = (bf16_t)a[j];
#pragma unroll
  for (int j = 0; j < 4; ++j) o[4 + j] = (bf16_t)b[j];
  *(bf16x8*)(dst + i) = o;
}

// ---------------------------------------------------------------------------
// All 4 weight matrices: fp32 [R][C] -> bf16 [C][R] tiled transpose-convert,
// single kernel. grid (160, 64): bx<64 Wq | <80 Wk | <96 Wv | <160 Wo.
// ---------------------------------------------------------------------------
__global__ __launch_bounds__(256) void wt_all(const float* __restrict__ Wq,
                                              const float* __restrict__ Wk,
                                              const float* __restrict__ Wv,
                                              const float* __restrict__ Wo,
                                              bf16_t* __restrict__ Wcat,
                                              bf16_t* __restrict__ Wot) {
  __shared__ float T[64][65];
  const int tid = threadIdx.x;
  const int bx = blockIdx.x;
  const float* src;
  bf16_t* dst;
  int C, c0;
  if (bx < 64)      { src = Wq; dst = Wcat;                         C = 4096; c0 = bx * 64; }
  else if (bx < 80) { src = Wk; dst = Wcat + (size_t)4096 * 4096;   C = 1024; c0 = (bx - 64) * 64; }
  else if (bx < 96) { src = Wv; dst = Wcat + (size_t)5120 * 4096;   C = 1024; c0 = (bx - 80) * 64; }
  else              { src = Wo; dst = Wot;                          C = 4096; c0 = (bx - 96) * 64; }
  const int r0 = blockIdx.y * 64;
#pragma unroll
  for (int i = 0; i < 16; ++i) {
    int idx = i * 256 + tid;
    int lr = idx >> 6, lc = idx & 63;
    T[lr][lc] = src[(size_t)(r0 + lr) * C + c0 + lc];
  }
  __syncthreads();
#pragma unroll
  for (int i = 0; i < 16; ++i) {
    int idx = i * 256 + tid;
    int lr = idx >> 6, lc = idx & 63;
    dst[(size_t)(c0 + lr) * 4096 + r0 + lc] = (bf16_t)T[lc][lr];
  }
}

// ---------------------------------------------------------------------------
// Deep-pipelined bf16 GEMM: C[M][N] = A[M][K] * Bt[N][K]^T
// BM=256, BN template (192 or 128), BK=64 as two 32-wide k-slabs.
// 512 threads = 8 waves (2 M-halves x 4 N-quarters); per-wave out 128 x BN/4.
// m201-style phase: ds_read issue -> stage issue -> s_barrier -> lgkmcnt(0) +
// sched_barrier(0) -> setprio(1) MFMA setprio(0) -> counted vmcnt -> s_barrier.
// Counted vmcnt never 0: slab staged at phase (T,j) is consumed at (T+1,j),
// the drain to N=own-issues-per-phase guarantees the oldest slab landed.
// XOR swizzle byte^=((byte>>9)&1)<<5; global source pre-swizzled (LDS dest
// linear for global_load_lds). Bijective XCD swizzle on 256 blocks.
// ---------------------------------------------------------------------------
template <int BN, bool OUT_BF16>
__global__ __launch_bounds__(512) void gemm8(const bf16_t* __restrict__ A,
                                             const bf16_t* __restrict__ Bt,
                                             void* __restrict__ C, int N, int K) {
  constexpr int BSLAB = BN * 32;          // elems per B slab
  constexpr int BUFE = 16384 + 2 * BSLAB; // elems per K-tile buffer
  constexpr int NF = BN / 64;             // B frags per wave (3 or 2)
  constexpr int WN = BN / 4;              // per-wave N span
  constexpr int BCH = BN * 4;             // 16B chunks per B slab
  __shared__ bf16_t sm[2 * BUFE];

  const int tid = threadIdx.x;
  const int lane = tid & 63;
  const int w = tid >> 6;
  const int wm = w >> 2, wn = w & 3;
  const int g = lane >> 4;
  const int r16 = lane & 15;

  // bijective XCD swizzle: 256 blocks, 32 per XCD, contiguous tx-range per XCD
  const int flat = blockIdx.y * 32 + blockIdx.x;
  const int xcd = flat & 7;
  const int i2 = flat >> 3;
  const int tx = xcd * 4 + (i2 & 3);
  const int ty = i2 >> 2;
  const int m0 = ty * 256;
  const int n0 = tx * BN;

  const int NT = K >> 6;

  f32x4 acc[8][NF] = {};

  // ---- staging helpers (issue only; wave-uniform LDS dest, swizzled src) ----
  auto stageA = [&](int T, int j) {
    bf16_t* base = sm + (T & 1) * BUFE + j * 8192;
#pragma unroll
    for (int cj = 0; cj < 2; ++cj) {
      int c = (w * 2 + cj) * 64 + lane;
      int p = c * 16;
      int l = p ^ (((p >> 9) & 1) << 5);
      int row = l >> 6, colb = l & 63;
      gload_lds16(A + (size_t)(m0 + row) * K + T * 64 + j * 32 + (colb >> 1),
                  base + (w * 2 + cj) * 512);
    }
  };
  auto stageB = [&](int T, int j) {
    bf16_t* base = sm + (T & 1) * BUFE + 16384 + j * BSLAB;
#pragma unroll
    for (int cj = 0; cj < (BCH + 511) / 512; ++cj) {
      int cbase = cj * 512 + w * 64;
      if (cbase < BCH) {
        int c = cbase + lane;
        int p = c * 16;
        int l = p ^ (((p >> 9) & 1) << 5);
        int row = l >> 6, colb = l & 63;
        gload_lds16(Bt + (size_t)(n0 + row) * K + T * 64 + j * 32 + (colb >> 1),
                    base + cbase * 8);
      }
    }
  };
  // per-wave issues per phase: A=2, B = 2 (BN=192, w<4) or 1
  auto waitbar = [&]() {
    if (BN == 192) {
      if (w < 4) asm volatile("s_waitcnt vmcnt(4)" ::: "memory");
      else       asm volatile("s_waitcnt vmcnt(3)" ::: "memory");
    } else {
      asm volatile("s_waitcnt vmcnt(3)" ::: "memory");
    }
    __builtin_amdgcn_s_barrier();
  };

  // prologue: stage tile 0 (slab 0 then slab 1); wait slab0; barrier
  stageA(0, 0); stageB(0, 0);
  stageA(0, 1); stageB(0, 1);
  waitbar();

#pragma unroll 2
  for (int T = 0; T < NT; ++T) {
    const bf16_t* abuf = sm + (T & 1) * BUFE;
    const bf16_t* bbuf = abuf + 16384;
#pragma unroll
    for (int j = 0; j < 2; ++j) {
      const bf16_t* as = abuf + j * 8192;
      const bf16_t* bs = bbuf + j * BSLAB;
      bf16x8 af[8];
      bf16x8 bfr[NF];
#pragma unroll
      for (int m = 0; m < 8; ++m) {
        int a = (wm * 128 + m * 16 + r16) * 64 + g * 16;
        a ^= ((a >> 9) & 1) << 5;
        af[m] = *(const bf16x8*)((const char*)as + a);
      }
#pragma unroll
      for (int n = 0; n < NF; ++n) {
        int a = (wn * WN + n * 16 + r16) * 64 + g * 16;
        a ^= ((a >> 9) & 1) << 5;
        bfr[n] = *(const bf16x8*)((const char*)bs + a);
      }
      if (T + 1 < NT) { stageA(T + 1, j); stageB(T + 1, j); }
      // m201 double-barrier phase: sync first, then wait own LDS reads.
      __builtin_amdgcn_s_barrier();
      asm volatile("s_waitcnt lgkmcnt(0)" ::: "memory");
      __builtin_amdgcn_sched_barrier(0);   // rule 18: keep MFMA below the wait
      __builtin_amdgcn_s_setprio(1);
#pragma unroll
      for (int m = 0; m < 8; ++m)
#pragma unroll
        for (int n = 0; n < NF; ++n)
          acc[m][n] = __builtin_amdgcn_mfma_f32_16x16x32_bf16(af[m], bfr[n],
                                                              acc[m][n], 0, 0, 0);
      __builtin_amdgcn_s_setprio(0);
      waitbar();
    }
  }

#pragma unroll
  for (int m = 0; m < 8; ++m)
#pragma unroll
    for (int n = 0; n < NF; ++n)
#pragma unroll
      for (int r = 0; r < 4; ++r) {
        int row = m0 + wm * 128 + m * 16 + g * 4 + r;
        int col = n0 + wn * WN + n * 16 + r16;
        if (OUT_BF16)
          ((bf16_t*)C)[(size_t)row * N + col] = (bf16_t)acc[m][n][r];
        else
          ((float*)C)[(size_t)row * N + col] = acc[m][n][r];
      }
}

// ---------------------------------------------------------------------------
// RoPE on q,k from QKV buffer; scatter into Qb[B,NH,S,HD], Kb[B,NKV,L,HD]
// grid (tokens, 20), block 256 (2 heads per block)
// ---------------------------------------------------------------------------
__global__ __launch_bounds__(256) void rope_pack(const bf16_t* __restrict__ QKV,
                                                 const float* __restrict__ rope,
                                                 bf16_t* __restrict__ Qb,
                                                 bf16_t* __restrict__ Kb) {
  const int tok = blockIdx.x;
  const int head = blockIdx.y * 2 + (threadIdx.x >> 7);
  const int d = threadIdx.x & 127;
  const int b = tok >> 10, s = tok & 1023;
  const int pos = PAST_ + s;
  const int off = head < NH_ ? head * HD_ : HID_ + (head - NH_) * HD_;
  const bf16_t* row = QKV + (size_t)tok * NQKV_;
  float x = (float)row[off + d];
  int dp = d < 64 ? d + 64 : d - 64;
  float xp = (float)row[off + dp];
  float c = rope[(size_t)(pos * 2) * HD_ + d];
  float sn = rope[(size_t)(pos * 2 + 1) * HD_ + d];
  float out = d < 64 ? x * c - xp * sn : x * c + xp * sn;
  if (head < NH_)
    Qb[((size_t)(b * NH_ + head) * S_ + s) * HD_ + d] = (bf16_t)out;
  else
    Kb[((size_t)(b * NKV_ + (head - NH_)) * L_ + PAST_ + s) * HD_ + d] = (bf16_t)out;
}

// ---------------------------------------------------------------------------
// Past KV: gather kv_cache[kv_lut] for l<PAST -> Kb direct, Vt transposed
// grid B*NKV*(PAST/64) = 256, block 256
// ---------------------------------------------------------------------------
__global__ __launch_bounds__(256) void past_kv(const float* __restrict__ cache,
                                               const int* __restrict__ kv_lut,
                                               bf16_t* __restrict__ Kb,
                                               bf16_t* __restrict__ Vt) {
  __shared__ bf16_t Vs[128][72];
  const int tid = threadIdx.x;
  const int lt = blockIdx.x & 15;
  const int h = (blockIdx.x >> 4) & 7;
  const int b = blockIdx.x >> 7;
  const int l0 = lt * 64;
#pragma unroll
  for (int i = 0; i < 32; ++i) {
    int idx = i * 256 + tid;
    int l = idx >> 7, d = idx & 127;
    int slot = kv_lut[b * L_ + l0 + l];
    float kv = cache[((size_t)slot * 2 * NKV_ + h) * HD_ + d];
    float vv = cache[(((size_t)slot * 2 + 1) * NKV_ + h) * HD_ + d];
    Kb[((size_t)(b * NKV_ + h) * L_ + l0 + l) * HD_ + d] = (bf16_t)kv;
    Vs[d][l] = (bf16_t)vv;
  }
  __syncthreads();
#pragma unroll
  for (int i = 0; i < 32; ++i) {
    int idx = i * 256 + tid;
    int d = idx >> 6, l = idx & 63;
    Vt[((size_t)(b * NKV_ + h) * HD_ + d) * L_ + l0 + l] = Vs[d][l];
  }
}

// ---------------------------------------------------------------------------
// New-token V: QKV v-part -> Vt transposed (l = PAST+s)
// grid B*NKV*(S/64) = 256, block 256
// ---------------------------------------------------------------------------
__global__ __launch_bounds__(256) void v_pack(const bf16_t* __restrict__ QKV,
                                              bf16_t* __restrict__ Vt) {
  __shared__ bf16_t Vs[128][72];
  const int tid = threadIdx.x;
  const int st = blockIdx.x & 15;
  const int h = (blockIdx.x >> 4) & 7;
  const int b = blockIdx.x >> 7;
  const int s0 = st * 64;
#pragma unroll
  for (int i = 0; i < 32; ++i) {
    int idx = i * 256 + tid;
    int sl = idx >> 7, d = idx & 127;
    Vs[d][sl] = QKV[(size_t)(b * S_ + s0 + sl) * NQKV_ + HID_ + NKV_ * HD_ + h * HD_ + d];
  }
  __syncthreads();
#pragma unroll
  for (int i = 0; i < 32; ++i) {
    int idx = i * 256 + tid;
    int d = idx >> 6, l = idx & 63;
    Vt[((size_t)(b * NKV_ + h) * HD_ + d) * L_ + PAST_ + s0 + l] = Vs[d][l];
  }
}

// ---------------------------------------------------------------------------
// Block-cooperative flash attention (unchanged from R3/R4).
// ---------------------------------------------------------------------------
__global__ __launch_bounds__(512) void attn(const bf16_t* __restrict__ Qb,
                                            const bf16_t* __restrict__ Kb,
                                            const bf16_t* __restrict__ Vt,
                                            bf16_t* __restrict__ Ctx) {
  // smem: K[2][8192] | V[2][8192] | P[8][1024]   (81920 bytes)
  __shared__ bf16_t smem[40960];

  const int tid = threadIdx.x;
  const int lane = tid & 63;
  const int w = tid >> 6;
  const int g = lane >> 4;
  const int r16 = lane & 15;
  const int rx = r16 & 7;

  const int id = blockIdx.x;
  const int kh = id & 7;
  const int b = (id >> 3) & 1;
  const int qh = (id >> 4) & 3;
  const int grp = id >> 6;                 // 0..7
  const int qc = grp < 4 ? 7 - grp : grp - 4;
  const int h = kh * G_ + qh;

  const int s0w = qc * 128 + w * 16;

  const bf16_t* qp = Qb + ((size_t)(b * NH_ + h) * S_ + s0w + r16) * HD_ + g * 8;
  bf16x8 qf[4];
#pragma unroll
  for (int ks = 0; ks < 4; ++ks) qf[ks] = *(const bf16x8*)(qp + ks * 32);

  const bf16_t* kbase = Kb + (size_t)(b * NKV_ + kh) * L_ * HD_;
  const bf16_t* vbase = Vt + (size_t)(b * NKV_ + kh) * HD_ * L_;

  // staging indices (per thread, fixed): 2 K chunks + 2 V chunks of 16B
  const int slot0 = w * 2;
  const int kl0 = slot0 * 4 + (lane >> 4);       // K tile row, rep 0
  const int kc0 = (lane & 15) ^ (kl0 & 7);       // swizzled source chunk
  const int kl1 = kl0 + 4;
  const int kc1 = (lane & 15) ^ (kl1 & 7);
  const int vd0 = slot0 * 8 + (lane >> 3);       // V tile row (d), rep 0
  const int vc0 = (lane & 7) ^ (vd0 & 7);
  const int vd1 = vd0 + 8;
  const int vc1 = (lane & 7) ^ (vd1 & 7);

  float m_run = -1e30f;   // running max for q = s0w + r16
  float s_run = 0.f;      // running denom
  f32x4 acc_o[8] = {};

  const float scale = 0.08838834764831845f;  // 1/sqrt(HD)
  const int qpos_base = PAST_ + s0w;
  const int qpos = qpos_base + r16;
  const int nt_ = 18 + 2 * qc;

  // prologue: stage tile 0 into buf 0
  {
    bf16_t* Kd = smem;
    bf16_t* Vd = smem + 16384;
    gload_lds16(kbase + (size_t)kl0 * HD_ + kc0 * 8, Kd + slot0 * 512);
    gload_lds16(kbase + (size_t)kl1 * HD_ + kc1 * 8, Kd + (slot0 + 1) * 512);
    gload_lds16(vbase + (size_t)vd0 * L_ + vc0 * 8, Vd + slot0 * 512);
    gload_lds16(vbase + (size_t)vd1 * L_ + vc1 * 8, Vd + (slot0 + 1) * 512);
  }
  __syncthreads();

  for (int t = 0; t < nt_; ++t) {
    const int cur = t & 1;
    const int lt = t * 64;

    // stage t+1 into the other buffer (overlaps with compute below)
    if (t + 1 < nt_) {
      const int ltn = lt + 64;
      bf16_t* Kd = smem + (cur ^ 1) * 8192;
      bf16_t* Vd = smem + 16384 + (cur ^ 1) * 8192;
      gload_lds16(kbase + (size_t)(ltn + kl0) * HD_ + kc0 * 8, Kd + slot0 * 512);
      gload_lds16(kbase + (size_t)(ltn + kl1) * HD_ + kc1 * 8, Kd + (slot0 + 1) * 512);
      gload_lds16(vbase + (size_t)vd0 * L_ + ltn + vc0 * 8, Vd + slot0 * 512);
      gload_lds16(vbase + (size_t)vd1 * L_ + ltn + vc1 * 8, Vd + (slot0 + 1) * 512);
    }

    const bf16_t* Kc = smem + cur * 8192;
    const bf16_t* Vc = smem + 16384 + cur * 8192;
    bf16_t* Pw = smem + 32768 + w * 1024;

    // QK^T swapped: sc[nt][r] = S[l = lt+nt*16+g*4+r][q = s0w+r16]
    f32x4 sc[4] = {};
#pragma unroll
    for (int nt = 0; nt < 4; ++nt) {
#pragma unroll
      for (int ks = 0; ks < 4; ++ks) {
        bf16x8 kf = *(const bf16x8*)&Kc[(nt * 16 + r16) * 128 + (((ks * 4 + g) ^ rx) << 3)];
        sc[nt] = __builtin_amdgcn_mfma_f32_16x16x32_bf16(kf, qf[ks], sc[nt], 0, 0, 0);
      }
    }

    // scale + mask + in-lane max
    const bool need_mask = (lt + 63) > qpos_base;
    float sv[4][4];
    float tmax = -1e30f;
#pragma unroll
    for (int nt = 0; nt < 4; ++nt)
#pragma unroll
      for (int r = 0; r < 4; ++r) {
        float v = sc[nt][r] * scale;
        if (need_mask) {
          int l = lt + nt * 16 + g * 4 + r;
          if (l > qpos) v = -1e30f;
        }
        sv[nt][r] = v;
        tmax = fmaxf(tmax, v);
      }
    tmax = fmaxf(tmax, __shfl_xor(tmax, 16, 64));
    tmax = fmaxf(tmax, __shfl_xor(tmax, 32, 64));

    // defer-max (T13, THR=8)
    if (!__all(tmax <= m_run + 8.f)) {
      float newm = fmaxf(m_run, tmax);
      float alpha = __expf(m_run - newm);
      m_run = newm;
      s_run *= alpha;
#pragma unroll
      for (int r = 0; r < 4; ++r) {
        float a = __shfl(alpha, g * 4 + r, 64);
#pragma unroll
        for (int d8 = 0; d8 < 8; ++d8) acc_o[d8][r] *= a;
      }
    }

    // P = exp(S - m), row-sum; pack 4 bf16 -> one b64 swizzled LDS write per nt
    float psum = 0.f;
#pragma unroll
    for (int nt = 0; nt < 4; ++nt) {
      bf16x4 pk;
#pragma unroll
      for (int r = 0; r < 4; ++r) {
        float pv = __expf(sv[nt][r] - m_run);
        psum += pv;
        pk[r] = (bf16_t)pv;
      }
      *(bf16x4*)&Pw[r16 * 64 + (((nt * 2 + (g >> 1)) ^ rx) << 3) + (g & 1) * 4] = pk;
    }
    psum += __shfl_xor(psum, 16, 64);
    psum += __shfl_xor(psum, 32, 64);
    s_run += psum;

    // PV: A = P rows(q), B = V rows(d), both from swizzled LDS
#pragma unroll
    for (int ks2 = 0; ks2 < 2; ++ks2) {
      bf16x8 pa = *(const bf16x8*)&Pw[r16 * 64 + (((ks2 * 4 + g) ^ rx) << 3)];
#pragma unroll
      for (int d8 = 0; d8 < 8; ++d8) {
        bf16x8 vf = *(const bf16x8*)&Vc[(d8 * 16 + r16) * 64 + (((ks2 * 4 + g) ^ rx) << 3)];
        acc_o[d8] = __builtin_amdgcn_mfma_f32_16x16x32_bf16(pa, vf, acc_o[d8], 0, 0, 0);
      }
    }

    __syncthreads();  // drains vmcnt (stage t+1 done) + all waves done with cur
  }

  float inv[4];
#pragma unroll
  for (int r = 0; r < 4; ++r) inv[r] = 1.f / __shfl(s_run, g * 4 + r, 64);
#pragma unroll
  for (int d8 = 0; d8 < 8; ++d8)
#pragma unroll
    for (int r = 0; r < 4; ++r) {
      int tok = b * S_ + s0w + g * 4 + r;
      int col = h * HD_ + d8 * 16 + r16;
      Ctx[(size_t)tok * HID_ + col] = (bf16_t)(acc_o[d8][r] * inv[r]);
    }
}

// ---------------------------------------------------------------------------
extern "C" void kernel_launch(void* const* d_in, const int* in_sizes, int n_in,
                              void* d_out, int out_size, void* d_ws, size_t ws_size,
                              hipStream_t stream) {
  const float* hidden = (const float*)d_in[0];
  const float* kv_cache = (const float*)d_in[1];
  const float* rope = (const float*)d_in[2];
  const float* Wq = (const float*)d_in[3];
  const float* Wk = (const float*)d_in[4];
  const float* Wv = (const float*)d_in[5];
  const float* Wo = (const float*)d_in[6];
  const int* kv_lut = (const int*)d_in[9];
  float* out = (float*)d_out;

  // workspace layout (bf16 elements)
  bf16_t* Xb = (bf16_t*)d_ws;                      //  2048*4096
  bf16_t* Wcat = Xb + (size_t)2048 * 4096;         //  6144*4096 (B^T: [n][k])
  bf16_t* Wot = Wcat + (size_t)6144 * 4096;        //  4096*4096
  bf16_t* QKVb = Wot + (size_t)4096 * 4096;        //  2048*6144
  bf16_t* Qb = QKVb + (size_t)2048 * 6144;         //  B*NH*S*HD
  bf16_t* Kb = Qb + (size_t)B_ * NH_ * S_ * HD_;   //  B*NKV*L*HD
  bf16_t* Vt = Kb + (size_t)B_ * NKV_ * L_ * HD_;  //  B*NKV*HD*L
  bf16_t* Ctx = Xb;                                //  reuse (Xb dead after GEMM1)

  // 1. converts / transposes
  cvt_bf16x8<<<4096, 256, 0, stream>>>(hidden, Xb);
  wt_all<<<dim3(160, 64), 256, 0, stream>>>(Wq, Wk, Wv, Wo, Wcat, Wot);

  // 2. QKV projection (BM=256, BN=192 -> 32x8 = 256 blocks, 1/CU)
  gemm8<192, true><<<dim3(32, 8), 512, 0, stream>>>(Xb, Wcat, QKVb, NQKV_, HID_);

  // 3. RoPE + KV pack
  rope_pack<<<dim3(2048, 20), 256, 0, stream>>>(QKVb, rope, Qb, Kb);
  past_kv<<<256, 256, 0, stream>>>(kv_cache, kv_lut, Kb, Vt);
  v_pack<<<256, 256, 0, stream>>>(QKVb, Vt);

  // 4. attention
  attn<<<512, 512, 0, stream>>>(Qb, Kb, Vt, Ctx);

  // 5. output projection -> fp32 d_out (BM=256, BN=128 -> 32x8 = 256 blocks)
  gemm8<128, false><<<dim3(32, 8), 512, 0, stream>>>(Ctx, Wot, out, HID_, HID_);
}